// Round 6
// baseline (3650.388 us; speedup 1.0000x reference)
//
#include <hip/hip_runtime.h>
#include <stdint.h>

// GGNN, collapsed:
//   s_t[n] = sum_{e: dst=n, type=t} x[src[e]]          (gather from bf16 mirror xb)
//   gi = s @ Wc^T + typed bias + b_ih                  (MFMA 128x128 tiles, K=384, hi/lo)
//   k_gru_gh: gh = x @ W_hh^T in-register (16x16x32 MFMA, no LDS/barriers) + GRU -> x, xb
// Weights W = hi + lo bf16 split => ~16-bit effective mantissa. x master state fp32.

typedef __bf16 bf16;
typedef __bf16 v8bf  __attribute__((ext_vector_type(8)));
typedef __bf16 v2bf  __attribute__((ext_vector_type(2)));
typedef float  v16f  __attribute__((ext_vector_type(16)));
typedef float  v4f   __attribute__((ext_vector_type(4)));

__device__ __forceinline__ float sigf(float a){ return 1.0f/(1.0f+__expf(-a)); }

__global__ void k_diag(float* out, int n, float v){
  int i = threadIdx.x; if(i<n) out[i] = v;
}

__global__ void k_embed(const int* __restrict__ xtype, const int* __restrict__ xtok,
                        const float* __restrict__ xsmall,
                        const float* __restrict__ temb, const float* __restrict__ kemb,
                        float* __restrict__ x, bf16* __restrict__ xb, int use_xb, int N){
  int n = blockIdx.x; int j = threadIdx.x;
  if(n>=N) return;
  float v;
  if(j<32)       v = temb[xtype[n]*32 + j];
  else if(j<64)  v = kemb[xtok[n]*32 + (j-32)];
  else           v = xsmall[(size_t)n*64 + (j-64)];
  x[(size_t)n*128 + j] = v;
  if(use_xb) xb[(size_t)n*128 + j] = (bf16)v;
}

// Wc[o2][K] = sum_k2 W_ih[o2,k2] * msg_W[K>>7][k2][K&127]
__global__ void k_wcomb(const float* __restrict__ W_ih, const float* __restrict__ msg_W,
                        float* __restrict__ Wc){
  int i = blockIdx.x*256 + threadIdx.x;
  if(i >= 147456) return;
  int o2 = i/384, K = i%384;
  const float* wr = W_ih + o2*128;
  const float* mc = msg_W + (K>>7)*16384 + (K&127);
  float acc = 0.f;
  #pragma unroll 4
  for(int k2=0;k2<128;k2++) acc += wr[k2]*mc[k2*128];
  Wc[i] = acc;
}

// mbp[t][o2] = sum_k2 W_ih[o2,k2]*msg_b[t,k2]
__global__ void k_mbp(const float* __restrict__ W_ih, const float* __restrict__ msg_b,
                      float* __restrict__ mbp){
  int i = blockIdx.x*256 + threadIdx.x;
  if(i >= 1152) return;
  int t = i/384, o2 = i%384;
  const float* wr = W_ih + o2*128;
  const float* mb = msg_b + t*128;
  float acc = 0.f;
  #pragma unroll 4
  for(int k2=0;k2<128;k2++) acc += wr[k2]*mb[k2];
  mbp[i] = acc;
}

// hi/lo split. layout: [0,147456) Wc [o=384][K=384]; [147456,196608) W_hh [o=384][k=128]
__global__ void k_wprep(const float* __restrict__ Wc, const float* __restrict__ W_hh,
                        bf16* __restrict__ Whi, bf16* __restrict__ Wlo){
  int i = blockIdx.x*256 + threadIdx.x;
  if(i >= 196608) return;
  float w = (i < 147456) ? Wc[i] : W_hh[i-147456];
  bf16 h = (bf16)w;
  float lo = w - (float)h;
  Whi[i] = h; Wlo[i] = (bf16)lo;
}

__global__ void k_hist3(const int* __restrict__ dst, const int* __restrict__ et,
                        int* __restrict__ deg3, int E){
  int e = blockIdx.x*blockDim.x + threadIdx.x;
  if(e<E) atomicAdd(&deg3[dst[e]*3 + et[e]], 1);
}

__global__ void k_scan1(const int* __restrict__ deg, int n, int* __restrict__ part, int* __restrict__ bsum){
  __shared__ int s[256];
  int t = threadIdx.x;
  int base = blockIdx.x*1024 + t*4;
  int v[4]; int sum=0;
  #pragma unroll
  for(int k=0;k<4;k++){ int i=base+k; int d=(i<n)?deg[i]:0; sum+=d; v[k]=sum; }
  s[t]=sum; __syncthreads();
  for(int off=1;off<256;off<<=1){
    int add = (t>=off)? s[t-off] : 0;
    __syncthreads();
    s[t]+=add;
    __syncthreads();
  }
  int excl = (t>0)? s[t-1] : 0;
  #pragma unroll
  for(int k=0;k<4;k++){ int i=base+k; if(i<n) part[i]=v[k]+excl; }
  if(t==255) bsum[blockIdx.x] = s[255];
}

__global__ void k_scan2(const int* __restrict__ bsum, int nb, int* __restrict__ carry){
  if(threadIdx.x==0 && blockIdx.x==0){
    int c=0;
    for(int b=0;b<nb;b++){ carry[b]=c; c+=bsum[b]; }
  }
}

__global__ void k_finalize(const int* __restrict__ part, const int* __restrict__ deg,
                           const int* __restrict__ carry, int n,
                           int* __restrict__ rowptr, int* __restrict__ cursor){
  int i = blockIdx.x*blockDim.x + threadIdx.x;
  if(i>=n) return;
  int incl = part[i] + carry[i>>10];
  rowptr[i+1] = incl;
  cursor[i] = incl - deg[i];
  if(i==0) rowptr[0]=0;
}

__global__ void k_fill3(const int* __restrict__ src, const int* __restrict__ dst,
                        const int* __restrict__ et, int* __restrict__ cursor,
                        int* __restrict__ pay, int E){
  int e = blockIdx.x*blockDim.x + threadIdx.x;
  if(e>=E) return;
  int pos = atomicAdd(&cursor[dst[e]*3 + et[e]], 1);
  pay[pos] = src[e];
}

// gather from bf16 mirror: s[n, t*128+c] = sum typed in-edges xb[src]
__global__ void k_gather3_b(const bf16* __restrict__ xb, const int* __restrict__ rp3,
                            const int* __restrict__ pay, bf16* __restrict__ s, int N){
  int n = blockIdx.x*4 + (threadIdx.x>>6);
  if(n>=N) return;
  int lane = threadIdx.x & 63;
  int c = lane*2;
  int b = n*3;
  int e0=rp3[b], e1=rp3[b+1], e2=rp3[b+2], e3=rp3[b+3];
  float a0=0.f,b0=0.f,a1=0.f,b1=0.f,a2=0.f,b2=0.f;
  for(int i=e0;i<e1;i++){ v2bf v = *(const v2bf*)&xb[(size_t)pay[i]*128 + c]; a0+=(float)v[0]; b0+=(float)v[1]; }
  for(int i=e1;i<e2;i++){ v2bf v = *(const v2bf*)&xb[(size_t)pay[i]*128 + c]; a1+=(float)v[0]; b1+=(float)v[1]; }
  for(int i=e2;i<e3;i++){ v2bf v = *(const v2bf*)&xb[(size_t)pay[i]*128 + c]; a2+=(float)v[0]; b2+=(float)v[1]; }
  size_t o = (size_t)n*384 + c;
  v2bf t;
  t[0]=(bf16)a0; t[1]=(bf16)b0; *(v2bf*)&s[o]     = t;
  t[0]=(bf16)a1; t[1]=(bf16)b1; *(v2bf*)&s[o+128] = t;
  t[0]=(bf16)a2; t[1]=(bf16)b2; *(v2bf*)&s[o+256] = t;
}

// fallback gather from fp32 x (used only if ws too small for xb)
__global__ void k_gather3_f(const float* __restrict__ x, const int* __restrict__ rp3,
                            const int* __restrict__ pay, bf16* __restrict__ s, int N){
  int n = blockIdx.x*4 + (threadIdx.x>>6);
  if(n>=N) return;
  int lane = threadIdx.x & 63;
  int c = lane*2;
  int b = n*3;
  int e0=rp3[b], e1=rp3[b+1], e2=rp3[b+2], e3=rp3[b+3];
  float a0=0.f,b0=0.f,a1=0.f,b1=0.f,a2=0.f,b2=0.f;
  for(int i=e0;i<e1;i++){ float2 v = *(const float2*)&x[(size_t)pay[i]*128 + c]; a0+=v.x; b0+=v.y; }
  for(int i=e1;i<e2;i++){ float2 v = *(const float2*)&x[(size_t)pay[i]*128 + c]; a1+=v.x; b1+=v.y; }
  for(int i=e2;i<e3;i++){ float2 v = *(const float2*)&x[(size_t)pay[i]*128 + c]; a2+=v.x; b2+=v.y; }
  size_t o = (size_t)n*384 + c;
  v2bf t;
  t[0]=(bf16)a0; t[1]=(bf16)b0; *(v2bf*)&s[o]     = t;
  t[0]=(bf16)a1; t[1]=(bf16)b1; *(v2bf*)&s[o+128] = t;
  t[0]=(bf16)a2; t[1]=(bf16)b2; *(v2bf*)&s[o+256] = t;
}

// gi = s @ Wc^T + b_ih + typed deg bias.  128x128 block tile, wave 64x64 (2x2 of
// 32x32x16), BK=64, hi/lo weights. Proven structure (round 3).
#define LDSTR 72
__global__ __launch_bounds__(256) void k_gemm_gi(
    const bf16* __restrict__ s, int M,
    const bf16* __restrict__ Whi, const bf16* __restrict__ Wlo,
    const int* __restrict__ deg3, const float* __restrict__ mbp,
    const float* __restrict__ b_ih, bf16* __restrict__ gi)
{
  __shared__ bf16 As[128*LDSTR];
  __shared__ bf16 Bh[128*LDSTR];
  __shared__ bf16 Bl[128*LDSTR];
  int tid = threadIdx.x;
  int colBase = blockIdx.x * 128;
  int rowBase = blockIdx.y * 128;
  const bf16* Bhi = Whi + (size_t)colBase*384;
  const bf16* Blo = Wlo + (size_t)colBase*384;
  int lane = tid & 63, wave = tid >> 6;
  int wm = (wave&1)*64, wn = (wave>>1)*64;
  int lrow = lane & 31, lk8 = (lane>>5)*8;

  v16f acc[2][2] = {};

  for(int k0=0; k0<384; k0+=64){
    #pragma unroll
    for(int p=0;p<4;p++){
      int ch = tid + p*256;
      int row = ch>>3;
      int c8 = (ch&7)*8;
      int gr = rowBase + row; if(gr >= M) gr = M-1;
      *(v8bf*)&As[row*LDSTR + c8] = *(const v8bf*)(s + (size_t)gr*384 + k0 + c8);
      size_t bo = (size_t)row*384 + k0 + c8;
      *(v8bf*)&Bh[row*LDSTR + c8] = *(const v8bf*)(Bhi + bo);
      *(v8bf*)&Bl[row*LDSTR + c8] = *(const v8bf*)(Blo + bo);
    }
    __syncthreads();
    #pragma unroll
    for(int ks=0;ks<4;ks++){
      int kb = ks*16 + lk8;
      v8bf a0  = *(const v8bf*)&As[(wm     + lrow)*LDSTR + kb];
      v8bf a1  = *(const v8bf*)&As[(wm+32  + lrow)*LDSTR + kb];
      v8bf bh0 = *(const v8bf*)&Bh[(wn     + lrow)*LDSTR + kb];
      v8bf bh1 = *(const v8bf*)&Bh[(wn+32  + lrow)*LDSTR + kb];
      v8bf bl0 = *(const v8bf*)&Bl[(wn     + lrow)*LDSTR + kb];
      v8bf bl1 = *(const v8bf*)&Bl[(wn+32  + lrow)*LDSTR + kb];
      acc[0][0] = __builtin_amdgcn_mfma_f32_32x32x16_bf16(a0, bh0, acc[0][0], 0,0,0);
      acc[0][1] = __builtin_amdgcn_mfma_f32_32x32x16_bf16(a0, bh1, acc[0][1], 0,0,0);
      acc[1][0] = __builtin_amdgcn_mfma_f32_32x32x16_bf16(a1, bh0, acc[1][0], 0,0,0);
      acc[1][1] = __builtin_amdgcn_mfma_f32_32x32x16_bf16(a1, bh1, acc[1][1], 0,0,0);
      acc[0][0] = __builtin_amdgcn_mfma_f32_32x32x16_bf16(a0, bl0, acc[0][0], 0,0,0);
      acc[0][1] = __builtin_amdgcn_mfma_f32_32x32x16_bf16(a0, bl1, acc[0][1], 0,0,0);
      acc[1][0] = __builtin_amdgcn_mfma_f32_32x32x16_bf16(a1, bl0, acc[1][0], 0,0,0);
      acc[1][1] = __builtin_amdgcn_mfma_f32_32x32x16_bf16(a1, bl1, acc[1][1], 0,0,0);
    }
    __syncthreads();
  }

  // C/D (32x32): col = lane&31, row = (r&3) + 8*(r>>2) + 4*(lane>>5)
  int rowq4 = 4*(lane>>5);
  #pragma unroll
  for(int mt=0;mt<2;mt++){
    #pragma unroll
    for(int nt=0;nt<2;nt++){
      int colg = colBase + wn + nt*32 + lrow;
      float bb  = b_ih[colg];
      float mb0 = mbp[colg], mb1 = mbp[384+colg], mb2 = mbp[768+colg];
      #pragma unroll
      for(int r=0;r<16;r++){
        int gr = rowBase + wm + mt*32 + (r&3) + 8*(r>>2) + rowq4;
        if(gr >= M) continue;
        const int* dq = &deg3[gr*3];
        float v = acc[mt][nt][r] + bb + dq[0]*mb0 + dq[1]*mb1 + dq[2]*mb2;
        gi[(size_t)gr*384 + colg] = (bf16)v;
      }
    }
  }
}

// Fused gh-GEMM + GRU. No LDS, no barriers. 4 waves/block, wave = 16 rows x 384 cols
// of gh via 16x16x32 MFMAs (24 independent 8-deep chains). A-frags from fp32 x
// (in-register bf16 convert); B-frags direct from L2-resident W_hh hi/lo.
// 16x16 C/D: col = lane&15, row = (lane>>4)*4 + reg  => lane owns all 3 gates of
// feature jf = s*16 + (lane&15). GRU fully in-register; x updated in place.
__global__ __launch_bounds__(256) void k_gru_gh(
    float* __restrict__ x, bf16* __restrict__ xb, int use_xb,
    const bf16* __restrict__ Whh_hi, const bf16* __restrict__ Whh_lo,
    const bf16* __restrict__ gi, const float* __restrict__ b_hh, int M)
{
  int tid = threadIdx.x, lane = tid & 63, wave = tid >> 6;
  int row0 = blockIdx.x*64 + wave*16;
  int m = lane & 15, q = lane >> 4;

  // A-frags: A[m][k], k = q*8 + j + 32t
  v8bf af[4];
  {
    int gr = row0 + m; if(gr >= M) gr = M-1;
    const float* xr = x + (size_t)gr*128 + q*8;
    #pragma unroll
    for(int t=0;t<4;t++){
      float4 f0 = *(const float4*)(xr + t*32);
      float4 f1 = *(const float4*)(xr + t*32 + 4);
      v8bf a;
      a[0]=(bf16)f0.x; a[1]=(bf16)f0.y; a[2]=(bf16)f0.z; a[3]=(bf16)f0.w;
      a[4]=(bf16)f1.x; a[5]=(bf16)f1.y; a[6]=(bf16)f1.z; a[7]=(bf16)f1.w;
      af[t]=a;
    }
  }

  v4f acc[3][8] = {};
  #pragma unroll
  for(int c=0;c<3;c++){
    #pragma unroll
    for(int s=0;s<8;s++){
      int n = c*128 + s*16 + m;         // output col (gate c, feature s*16+m)
      const bf16* wh = Whh_hi + (size_t)n*128 + q*8;
      const bf16* wl = Whh_lo + (size_t)n*128 + q*8;
      v4f a4 = acc[c][s];
      #pragma unroll
      for(int t=0;t<4;t++){
        a4 = __builtin_amdgcn_mfma_f32_16x16x32_bf16(af[t], *(const v8bf*)(wh + t*32), a4, 0,0,0);
        a4 = __builtin_amdgcn_mfma_f32_16x16x32_bf16(af[t], *(const v8bf*)(wl + t*32), a4, 0,0,0);
      }
      acc[c][s] = a4;
    }
  }

  #pragma unroll
  for(int s=0;s<8;s++){
    int jf = s*16 + m;
    float bh0 = b_hh[jf], bh1 = b_hh[128+jf], bh2 = b_hh[256+jf];
    #pragma unroll
    for(int reg=0;reg<4;reg++){
      int gr = row0 + q*4 + reg;
      if(gr >= M) continue;
      const bf16* gp = gi + (size_t)gr*384 + jf;
      float ir = (float)gp[0], iz = (float)gp[128], in_ = (float)gp[256];
      float hr = acc[0][s][reg] + bh0;
      float hz = acc[1][s][reg] + bh1;
      float hn = acc[2][s][reg] + bh2;
      float rg = sigf(ir + hr);
      float zg = sigf(iz + hz);
      float nn = tanhf(in_ + rg*hn);
      size_t xi = (size_t)gr*128 + jf;
      float xo = x[xi];
      float xv = (1.f - zg)*nn + zg*xo;
      x[xi] = xv;
      if(use_xb) xb[xi] = (bf16)xv;
    }
  }
}

__device__ __forceinline__ int lb_batch(const int* __restrict__ batch, int N, int g){
  int lo=0, hi=N;
  while(lo<hi){ int mid=(lo+hi)>>1; if(batch[mid]<g) lo=mid+1; else hi=mid; }
  return lo;
}

__global__ void k_pool2(const float* __restrict__ x, const int* __restrict__ batch,
                        float* __restrict__ pooled, int N){
  int g = blockIdx.x, slice = blockIdx.y;
  int j = threadIdx.x;
  int lo = lb_batch(batch,N,g), hi = lb_batch(batch,N,g+1);
  float acc = 0.f;
  for(int r=lo+slice; r<hi; r+=32) acc += x[(size_t)r*128 + j];
  atomicAdd(&pooled[g*128+j], acc);
}

__global__ void k_head(const float* __restrict__ pooled, const int* __restrict__ batch, int N,
                       const float* __restrict__ W1, const float* __restrict__ b1,
                       const float* __restrict__ W2, const float* __restrict__ b2,
                       float* __restrict__ out){
  int g = blockIdx.x; int j = threadIdx.x;
  __shared__ float p[128];
  __shared__ float red[128];
  int lo = lb_batch(batch,N,g), hi = lb_batch(batch,N,g+1);
  float c = (float)(hi-lo); if(c < 1.f) c = 1.f;
  p[j] = pooled[g*128+j] / c;
  __syncthreads();
  float acc = b1[j];
  #pragma unroll 4
  for(int i=0;i<128;i++) acc += W1[j*128+i]*p[i];
  float v = (acc>0.f?acc:0.f) * W2[j];
  red[j] = v; __syncthreads();
  for(int s=64;s>0;s>>=1){ if(j<s) red[j]+=red[j+s]; __syncthreads(); }
  if(j==0) out[g] = red[0] + b2[0];
}

extern "C" void kernel_launch(void* const* d_in, const int* in_sizes, int n_in,
                              void* d_out, int out_size, void* d_ws, size_t ws_size,
                              hipStream_t stream){
  const int*   x_type    = (const int*)d_in[0];
  const int*   x_tok     = (const int*)d_in[1];
  const float* x_small   = (const float*)d_in[2];
  const int*   edge_index= (const int*)d_in[3];
  const int*   edge_type = (const int*)d_in[4];
  const int*   batch     = (const int*)d_in[5];
  const float* type_emb  = (const float*)d_in[6];
  const float* tok_emb   = (const float*)d_in[7];
  const float* msg_W     = (const float*)d_in[8];
  const float* msg_b     = (const float*)d_in[9];
  const float* W_ih      = (const float*)d_in[10];
  const float* W_hh      = (const float*)d_in[11];
  const float* b_ih      = (const float*)d_in[12];
  const float* b_hh      = (const float*)d_in[13];
  const float* pW1       = (const float*)d_in[14];
  const float* pb1       = (const float*)d_in[15];
  const float* pW2       = (const float*)d_in[16];
  const float* pb2       = (const float*)d_in[17];
  float* out = (float*)d_out;

  int N = in_sizes[0];
  int E = in_sizes[3]/2;
  const int* src = edge_index;
  const int* dst = edge_index + E;
  int n3 = 3*N;
  int nch = (n3+1023)/1024;

  char* w = (char*)d_ws;
  size_t off = 0;
  auto alloc = [&](size_t bytes)->char*{ char* p = w + off; off += (bytes + 511) & ~511ull; return p; };
  float* x      = (float*)alloc((size_t)N*128*4);     // fp32 master (51.2 MB)
  bf16*  s      = (bf16*)alloc((size_t)N*384*2);      // gathered sums (76.8 MB)
  bf16*  gi     = (bf16*)alloc((size_t)N*384*2);      // gi buffer (76.8 MB)
  int*   deg3   = (int*)alloc((size_t)n3*4);
  int*   part   = (int*)alloc((size_t)n3*4);
  int*   rp3    = (int*)alloc((size_t)(n3+1)*4);
  int*   cursor = (int*)alloc((size_t)n3*4);
  int*   pay    = (int*)alloc((size_t)E*4);
  int*   bsum   = (int*)alloc((size_t)nch*4);
  int*   carry  = (int*)alloc((size_t)nch*4);
  float* Wc     = (float*)alloc((size_t)147456*4);
  bf16*  Whi    = (bf16*)alloc((size_t)196608*2);
  bf16*  Wlo    = (bf16*)alloc((size_t)196608*2);
  float* mbp    = (float*)alloc((size_t)1152*4);
  float* pooled = (float*)alloc(64*128*4);
  if(off > ws_size){
    k_diag<<<1,64,0,stream>>>(out, out_size, 1.0e6f + (float)(ws_size>>20));
    return;
  }
  size_t base_off = off;
  bf16* xb = (bf16*)alloc((size_t)N*128*2);           // bf16 mirror (25.6 MB), optional
  int use_xb = (off <= ws_size) ? 1 : 0;
  if(!use_xb) off = base_off;

  const int tb = 256;
  hipMemsetAsync(deg3, 0, (size_t)n3*4, stream);
  k_wcomb   <<<576, 256, 0, stream>>>(W_ih, msg_W, Wc);
  k_mbp     <<<5, 256, 0, stream>>>(W_ih, msg_b, mbp);
  k_wprep   <<<768, 256, 0, stream>>>(Wc, W_hh, Whi, Wlo);
  k_hist3   <<<(E+tb-1)/tb, tb, 0, stream>>>(dst, edge_type, deg3, E);
  k_scan1   <<<nch, 256, 0, stream>>>(deg3, n3, part, bsum);
  k_scan2   <<<1, 64, 0, stream>>>(bsum, nch, carry);
  k_finalize<<<(n3+tb-1)/tb, tb, 0, stream>>>(part, deg3, carry, n3, rp3, cursor);
  k_fill3   <<<(E+tb-1)/tb, tb, 0, stream>>>(src, dst, edge_type, cursor, pay, E);
  k_embed   <<<N, 128, 0, stream>>>(x_type, x_tok, x_small, type_emb, tok_emb, x, xb, use_xb, N);

  int mt = (N+127)/128;
  for(int it=0; it<8; it++){
    if(use_xb) k_gather3_b<<<(N+3)/4, 256, 0, stream>>>(xb, rp3, pay, s, N);
    else       k_gather3_f<<<(N+3)/4, 256, 0, stream>>>(x,  rp3, pay, s, N);
    k_gemm_gi<<<dim3(3, mt), 256, 0, stream>>>(s, N, Whi, Wlo, deg3, mbp, b_ih, gi);
    k_gru_gh <<<(N+63)/64, 256, 0, stream>>>(x, xb, use_xb, Whi+147456, Wlo+147456, gi, b_hh, N);
  }
  hipMemsetAsync(pooled, 0, 64*128*4, stream);
  k_pool2<<<dim3(64,32), 128, 0, stream>>>(x, batch, pooled, N);
  k_head <<<64, 128, 0, stream>>>(pooled, batch, N, pW1, pb1, pW2, pb2, out);
}

// Round 7
// 2320.781 us; speedup vs baseline: 1.5729x; 1.5729x over previous
//
#include <hip/hip_runtime.h>
#include <stdint.h>

// GGNN, collapsed + fully fused iteration:
//   s_t[n] = sum_{e:dst=n,type=t} xb[src[e]]     (k_gather3_b)
//   k_mega (per 64-row block): gi = s@Wc^T (K=384), gh = x@W_hh^T (K=128),
//     GRU in-register -> x (fp32 master), xb (bf16 mirror). No gi/gh buffers.
// Weights hi/lo bf16 split, PRE-PACKED in MFMA B-fragment order so every
// B-frag load is wave-uniform base + lane*16B (coalesced, L2-hot).
// Wave w owns col-tiles {w, w+4, w+8} => feature slice jf in [32w,32w+32)
// across all 3 gates for gi AND gh => GRU needs no data exchange.

typedef __bf16 bf16;
typedef __bf16 v8bf  __attribute__((ext_vector_type(8)));
typedef __bf16 v2bf  __attribute__((ext_vector_type(2)));
typedef float  v16f  __attribute__((ext_vector_type(16)));

__device__ __forceinline__ float sigf(float a){ return 1.0f/(1.0f+__expf(-a)); }

__global__ void k_diag(float* out, int n, float v){
  int i = threadIdx.x; if(i<n) out[i] = v;
}

__global__ void k_embed(const int* __restrict__ xtype, const int* __restrict__ xtok,
                        const float* __restrict__ xsmall,
                        const float* __restrict__ temb, const float* __restrict__ kemb,
                        float* __restrict__ x, bf16* __restrict__ xb, int N){
  int n = blockIdx.x; int j = threadIdx.x;
  if(n>=N) return;
  float v;
  if(j<32)       v = temb[xtype[n]*32 + j];
  else if(j<64)  v = kemb[xtok[n]*32 + (j-32)];
  else           v = xsmall[(size_t)n*64 + (j-64)];
  x[(size_t)n*128 + j] = v;
  xb[(size_t)n*128 + j] = (bf16)v;
}

// Wc[o2][K] = sum_k2 W_ih[o2,k2] * msg_W[K>>7][k2][K&127]
__global__ void k_wcomb(const float* __restrict__ W_ih, const float* __restrict__ msg_W,
                        float* __restrict__ Wc){
  int i = blockIdx.x*256 + threadIdx.x;
  if(i >= 147456) return;
  int o2 = i/384, K = i%384;
  const float* wr = W_ih + o2*128;
  const float* mc = msg_W + (K>>7)*16384 + (K&127);
  float acc = 0.f;
  #pragma unroll 4
  for(int k2=0;k2<128;k2++) acc += wr[k2]*mc[k2*128];
  Wc[i] = acc;
}

// mbp[t][o2] = sum_k2 W_ih[o2,k2]*msg_b[t,k2]
__global__ void k_mbp(const float* __restrict__ W_ih, const float* __restrict__ msg_b,
                      float* __restrict__ mbp){
  int i = blockIdx.x*256 + threadIdx.x;
  if(i >= 1152) return;
  int t = i/384, o2 = i%384;
  const float* wr = W_ih + o2*128;
  const float* mb = msg_b + t*128;
  float acc = 0.f;
  #pragma unroll 4
  for(int k2=0;k2<128;k2++) acc += wr[k2]*mb[k2];
  mbp[i] = acc;
}

// Pack weights into MFMA B-frag order, hi/lo split.
// gi (Wc, [384][384]): 12 tiles x 24 ksteps x 64 lanes x 8 elems -> 147456
// gh (W_hh, [384][128]): 12 tiles x 8 ksteps x 64 lanes x 8    -> 49152
// frag elem: n = tile*32 + (lane&31), k = ks*16 + (lane>>5)*8 + j
__global__ void k_wprep(const float* __restrict__ Wc, const float* __restrict__ W_hh,
                        bf16* __restrict__ WgiH, bf16* __restrict__ WgiL,
                        bf16* __restrict__ WghH, bf16* __restrict__ WghL){
  int i = blockIdx.x*256 + threadIdx.x;
  if(i >= 196608) return;
  float w;
  if(i < 147456){
    int tile = i/12288, rem = i%12288;
    int ks = rem/512, rem2 = rem%512;
    int lane = rem2/8, j = rem2%8;
    int n = tile*32 + (lane&31);
    int k = ks*16 + (lane>>5)*8 + j;
    w = Wc[n*384 + k];
    bf16 h = (bf16)w;
    WgiH[i] = h; WgiL[i] = (bf16)(w - (float)h);
  } else {
    int i2 = i - 147456;
    int tile = i2/4096, rem = i2%4096;
    int ks = rem/512, rem2 = rem%512;
    int lane = rem2/8, j = rem2%8;
    int n = tile*32 + (lane&31);
    int k = ks*16 + (lane>>5)*8 + j;
    w = W_hh[n*128 + k];
    bf16 h = (bf16)w;
    WghH[i2] = h; WghL[i2] = (bf16)(w - (float)h);
  }
}

__global__ void k_hist3(const int* __restrict__ dst, const int* __restrict__ et,
                        int* __restrict__ deg3, int E){
  int e = blockIdx.x*blockDim.x + threadIdx.x;
  if(e<E) atomicAdd(&deg3[dst[e]*3 + et[e]], 1);
}

__global__ void k_scan1(const int* __restrict__ deg, int n, int* __restrict__ part, int* __restrict__ bsum){
  __shared__ int s[256];
  int t = threadIdx.x;
  int base = blockIdx.x*1024 + t*4;
  int v[4]; int sum=0;
  #pragma unroll
  for(int k=0;k<4;k++){ int i=base+k; int d=(i<n)?deg[i]:0; sum+=d; v[k]=sum; }
  s[t]=sum; __syncthreads();
  for(int off=1;off<256;off<<=1){
    int add = (t>=off)? s[t-off] : 0;
    __syncthreads();
    s[t]+=add;
    __syncthreads();
  }
  int excl = (t>0)? s[t-1] : 0;
  #pragma unroll
  for(int k=0;k<4;k++){ int i=base+k; if(i<n) part[i]=v[k]+excl; }
  if(t==255) bsum[blockIdx.x] = s[255];
}

__global__ void k_scan2(const int* __restrict__ bsum, int nb, int* __restrict__ carry){
  if(threadIdx.x==0 && blockIdx.x==0){
    int c=0;
    for(int b=0;b<nb;b++){ carry[b]=c; c+=bsum[b]; }
  }
}

__global__ void k_finalize(const int* __restrict__ part, const int* __restrict__ deg,
                           const int* __restrict__ carry, int n,
                           int* __restrict__ rowptr, int* __restrict__ cursor){
  int i = blockIdx.x*blockDim.x + threadIdx.x;
  if(i>=n) return;
  int incl = part[i] + carry[i>>10];
  rowptr[i+1] = incl;
  cursor[i] = incl - deg[i];
  if(i==0) rowptr[0]=0;
}

__global__ void k_fill3(const int* __restrict__ src, const int* __restrict__ dst,
                        const int* __restrict__ et, int* __restrict__ cursor,
                        int* __restrict__ pay, int E){
  int e = blockIdx.x*blockDim.x + threadIdx.x;
  if(e>=E) return;
  int pos = atomicAdd(&cursor[dst[e]*3 + et[e]], 1);
  pay[pos] = src[e];
}

// gather from bf16 mirror: s[n, t*128+c] = sum typed in-edges xb[src]
__global__ void k_gather3_b(const bf16* __restrict__ xb, const int* __restrict__ rp3,
                            const int* __restrict__ pay, bf16* __restrict__ s, int N){
  int n = blockIdx.x*4 + (threadIdx.x>>6);
  if(n>=N) return;
  int lane = threadIdx.x & 63;
  int c = lane*2;
  int b = n*3;
  int e0=rp3[b], e1=rp3[b+1], e2=rp3[b+2], e3=rp3[b+3];
  float a0=0.f,b0=0.f,a1=0.f,b1=0.f,a2=0.f,b2=0.f;
  for(int i=e0;i<e1;i++){ v2bf v = *(const v2bf*)&xb[(size_t)pay[i]*128 + c]; a0+=(float)v[0]; b0+=(float)v[1]; }
  for(int i=e1;i<e2;i++){ v2bf v = *(const v2bf*)&xb[(size_t)pay[i]*128 + c]; a1+=(float)v[0]; b1+=(float)v[1]; }
  for(int i=e2;i<e3;i++){ v2bf v = *(const v2bf*)&xb[(size_t)pay[i]*128 + c]; a2+=(float)v[0]; b2+=(float)v[1]; }
  size_t o = (size_t)n*384 + c;
  v2bf t;
  t[0]=(bf16)a0; t[1]=(bf16)b0; *(v2bf*)&s[o]     = t;
  t[0]=(bf16)a1; t[1]=(bf16)b1; *(v2bf*)&s[o+128] = t;
  t[0]=(bf16)a2; t[1]=(bf16)b2; *(v2bf*)&s[o+256] = t;
}

// Fused gi+gh GEMM + GRU. 64-row block, 256 threads (4 waves).
// Wave w: col-tiles {w, w+4, w+8} (= feature slice [32w,32w+32) x gates 0..2),
// row-tiles {0,1}. acc: 6 v16f gi + 6 v16f gh = 192 VGPR.
// A staged in LDS (s in two K-halves, x converted to bf16).
// B read directly from L2 in packed frag order (coalesced 16B/lane).
#define SSTR 200   // 192+8 elems: 400B rows, 16B-aligned
#define XSTR 136   // 128+8
__global__ __launch_bounds__(256,2) void k_mega(
    const bf16* __restrict__ s, float* __restrict__ x, bf16* __restrict__ xb,
    const bf16* __restrict__ WgiH, const bf16* __restrict__ WgiL,
    const bf16* __restrict__ WghH, const bf16* __restrict__ WghL,
    const int* __restrict__ deg3, const float* __restrict__ mbp,
    const float* __restrict__ b_ih, const float* __restrict__ b_hh, int M)
{
  __shared__ bf16 Ss[64*SSTR];   // 25.0 KB
  __shared__ bf16 Ax[64*XSTR];   // 17.0 KB
  int tid = threadIdx.x, lane = tid & 63, w = tid >> 6;
  int lrow = lane & 31, q = lane >> 5;
  int row0 = blockIdx.x * 64;

  // stage x tile -> bf16 (64 x 128): 1024 v8 chunks, 4/thread
  #pragma unroll
  for(int p=0;p<4;p++){
    int ch = tid + p*256;
    int row = ch>>4, c8 = (ch&15)*8;
    int gr = row0 + row; if(gr >= M) gr = M-1;
    const float* ap = x + (size_t)gr*128 + c8;
    float4 f0 = *(const float4*)ap;
    float4 f1 = *(const float4*)(ap+4);
    v8bf t;
    t[0]=(bf16)f0.x; t[1]=(bf16)f0.y; t[2]=(bf16)f0.z; t[3]=(bf16)f0.w;
    t[4]=(bf16)f1.x; t[5]=(bf16)f1.y; t[6]=(bf16)f1.z; t[7]=(bf16)f1.w;
    *(v8bf*)&Ax[row*XSTR + c8] = t;
  }
  // stage s K-half 0 (k 0..192): 1536 chunks, 6/thread
  #pragma unroll
  for(int p=0;p<6;p++){
    int ch = tid + p*256;
    int row = ch/24, c8 = (ch%24)*8;
    int gr = row0 + row; if(gr >= M) gr = M-1;
    *(v8bf*)&Ss[row*SSTR + c8] = *(const v8bf*)(s + (size_t)gr*384 + c8);
  }
  __syncthreads();

  v16f agi[2][3] = {};
  v16f agh[2][3] = {};

  // ---- gh: K=128 over Ax ----
  #pragma unroll
  for(int ks=0; ks<8; ks++){
    int kb = ks*16 + q*8;
    v8bf a0 = *(const v8bf*)&Ax[(     lrow)*XSTR + kb];
    v8bf a1 = *(const v8bf*)&Ax[(32 + lrow)*XSTR + kb];
    #pragma unroll
    for(int ct=0; ct<3; ct++){
      int tile = ct*4 + w;
      size_t fo = ((size_t)(tile*8 + ks)*64 + lane)*8;
      v8bf bh = *(const v8bf*)(WghH + fo);
      v8bf bl = *(const v8bf*)(WghL + fo);
      agh[0][ct] = __builtin_amdgcn_mfma_f32_32x32x16_bf16(a0, bh, agh[0][ct], 0,0,0);
      agh[1][ct] = __builtin_amdgcn_mfma_f32_32x32x16_bf16(a1, bh, agh[1][ct], 0,0,0);
      agh[0][ct] = __builtin_amdgcn_mfma_f32_32x32x16_bf16(a0, bl, agh[0][ct], 0,0,0);
      agh[1][ct] = __builtin_amdgcn_mfma_f32_32x32x16_bf16(a1, bl, agh[1][ct], 0,0,0);
    }
  }

  // ---- gi K-half 0 (ks 0..11) ----
  #pragma unroll
  for(int ks=0; ks<12; ks++){
    int kb = ks*16 + q*8;
    v8bf a0 = *(const v8bf*)&Ss[(     lrow)*SSTR + kb];
    v8bf a1 = *(const v8bf*)&Ss[(32 + lrow)*SSTR + kb];
    #pragma unroll
    for(int ct=0; ct<3; ct++){
      int tile = ct*4 + w;
      size_t fo = ((size_t)(tile*24 + ks)*64 + lane)*8;
      v8bf bh = *(const v8bf*)(WgiH + fo);
      v8bf bl = *(const v8bf*)(WgiL + fo);
      agi[0][ct] = __builtin_amdgcn_mfma_f32_32x32x16_bf16(a0, bh, agi[0][ct], 0,0,0);
      agi[1][ct] = __builtin_amdgcn_mfma_f32_32x32x16_bf16(a1, bh, agi[1][ct], 0,0,0);
      agi[0][ct] = __builtin_amdgcn_mfma_f32_32x32x16_bf16(a0, bl, agi[0][ct], 0,0,0);
      agi[1][ct] = __builtin_amdgcn_mfma_f32_32x32x16_bf16(a1, bl, agi[1][ct], 0,0,0);
    }
  }
  __syncthreads();
  // stage s K-half 1 (k 192..384)
  #pragma unroll
  for(int p=0;p<6;p++){
    int ch = tid + p*256;
    int row = ch/24, c8 = (ch%24)*8;
    int gr = row0 + row; if(gr >= M) gr = M-1;
    *(v8bf*)&Ss[row*SSTR + c8] = *(const v8bf*)(s + (size_t)gr*384 + 192 + c8);
  }
  __syncthreads();
  // ---- gi K-half 1 (ks 12..23) ----
  #pragma unroll
  for(int ks2=0; ks2<12; ks2++){
    int kb = ks2*16 + q*8;
    int ks = ks2 + 12;
    v8bf a0 = *(const v8bf*)&Ss[(     lrow)*SSTR + kb];
    v8bf a1 = *(const v8bf*)&Ss[(32 + lrow)*SSTR + kb];
    #pragma unroll
    for(int ct=0; ct<3; ct++){
      int tile = ct*4 + w;
      size_t fo = ((size_t)(tile*24 + ks)*64 + lane)*8;
      v8bf bh = *(const v8bf*)(WgiH + fo);
      v8bf bl = *(const v8bf*)(WgiL + fo);
      agi[0][ct] = __builtin_amdgcn_mfma_f32_32x32x16_bf16(a0, bh, agi[0][ct], 0,0,0);
      agi[1][ct] = __builtin_amdgcn_mfma_f32_32x32x16_bf16(a1, bh, agi[1][ct], 0,0,0);
      agi[0][ct] = __builtin_amdgcn_mfma_f32_32x32x16_bf16(a0, bl, agi[0][ct], 0,0,0);
      agi[1][ct] = __builtin_amdgcn_mfma_f32_32x32x16_bf16(a1, bl, agi[1][ct], 0,0,0);
    }
  }

  // ---- GRU epilogue, in-register. jf = this lane's feature. ----
  int jf = w*32 + lrow;
  float bi0 = b_ih[jf],     bh0 = b_hh[jf];
  float bi1 = b_ih[128+jf], bh1 = b_hh[128+jf];
  float bi2 = b_ih[256+jf], bh2 = b_hh[256+jf];
  float mb[3][3];
  #pragma unroll
  for(int t=0;t<3;t++){
    mb[t][0] = mbp[t*384 + jf];
    mb[t][1] = mbp[t*384 + 128 + jf];
    mb[t][2] = mbp[t*384 + 256 + jf];
  }
  int rq4 = 4*q;
  #pragma unroll
  for(int rt=0; rt<2; rt++){
    #pragma unroll
    for(int r=0;r<16;r++){
      int gr = row0 + rt*32 + (r&3) + 8*(r>>2) + rq4;
      if(gr >= M) continue;
      const int* dq = &deg3[gr*3];
      float d0 = (float)dq[0], d1 = (float)dq[1], d2 = (float)dq[2];
      float ir  = agi[rt][0][r] + bi0 + d0*mb[0][0] + d1*mb[1][0] + d2*mb[2][0];
      float iz  = agi[rt][1][r] + bi1 + d0*mb[0][1] + d1*mb[1][1] + d2*mb[2][1];
      float in_ = agi[rt][2][r] + bi2 + d0*mb[0][2] + d1*mb[1][2] + d2*mb[2][2];
      float hr  = agh[rt][0][r] + bh0;
      float hz  = agh[rt][1][r] + bh1;
      float hn  = agh[rt][2][r] + bh2;
      float rg = sigf(ir + hr);
      float zg = sigf(iz + hz);
      float nn = tanhf(in_ + rg*hn);
      size_t xi = (size_t)gr*128 + jf;
      float xo = x[xi];
      float xv = (1.f - zg)*nn + zg*xo;
      x[xi] = xv;
      xb[xi] = (bf16)xv;
    }
  }
}

__device__ __forceinline__ int lb_batch(const int* __restrict__ batch, int N, int g){
  int lo=0, hi=N;
  while(lo<hi){ int mid=(lo+hi)>>1; if(batch[mid]<g) lo=mid+1; else hi=mid; }
  return lo;
}

__global__ void k_pool2(const float* __restrict__ x, const int* __restrict__ batch,
                        float* __restrict__ pooled, int N){
  int g = blockIdx.x, slice = blockIdx.y;
  int j = threadIdx.x;
  int lo = lb_batch(batch,N,g), hi = lb_batch(batch,N,g+1);
  float acc = 0.f;
  for(int r=lo+slice; r<hi; r+=32) acc += x[(size_t)r*128 + j];
  atomicAdd(&pooled[g*128+j], acc);
}

__global__ void k_head(const float* __restrict__ pooled, const int* __restrict__ batch, int N,
                       const float* __restrict__ W1, const float* __restrict__ b1,
                       const float* __restrict__ W2, const float* __restrict__ b2,
                       float* __restrict__ out){
  int g = blockIdx.x; int j = threadIdx.x;
  __shared__ float p[128];
  __shared__ float red[128];
  int lo = lb_batch(batch,N,g), hi = lb_batch(batch,N,g+1);
  float c = (float)(hi-lo); if(c < 1.f) c = 1.f;
  p[j] = pooled[g*128+j] / c;
  __syncthreads();
  float acc = b1[j];
  #pragma unroll 4
  for(int i=0;i<128;i++) acc += W1[j*128+i]*p[i];
  float v = (acc>0.f?acc:0.f) * W2[j];
  red[j] = v; __syncthreads();
  for(int s=64;s>0;s>>=1){ if(j<s) red[j]+=red[j+s]; __syncthreads(); }
  if(j==0) out[g] = red[0] + b2[0];
}

extern "C" void kernel_launch(void* const* d_in, const int* in_sizes, int n_in,
                              void* d_out, int out_size, void* d_ws, size_t ws_size,
                              hipStream_t stream){
  const int*   x_type    = (const int*)d_in[0];
  const int*   x_tok     = (const int*)d_in[1];
  const float* x_small   = (const float*)d_in[2];
  const int*   edge_index= (const int*)d_in[3];
  const int*   edge_type = (const int*)d_in[4];
  const int*   batch     = (const int*)d_in[5];
  const float* type_emb  = (const float*)d_in[6];
  const float* tok_emb   = (const float*)d_in[7];
  const float* msg_W     = (const float*)d_in[8];
  const float* msg_b     = (const float*)d_in[9];
  const float* W_ih      = (const float*)d_in[10];
  const float* W_hh      = (const float*)d_in[11];
  const float* b_ih      = (const float*)d_in[12];
  const float* b_hh      = (const float*)d_in[13];
  const float* pW1       = (const float*)d_in[14];
  const float* pb1       = (const float*)d_in[15];
  const float* pW2       = (const float*)d_in[16];
  const float* pb2       = (const float*)d_in[17];
  float* out = (float*)d_out;

  int N = in_sizes[0];
  int E = in_sizes[3]/2;
  const int* src = edge_index;
  const int* dst = edge_index + E;
  int n3 = 3*N;
  int nch = (n3+1023)/1024;

  char* w = (char*)d_ws;
  size_t off = 0;
  auto alloc = [&](size_t bytes)->char*{ char* p = w + off; off += (bytes + 511) & ~511ull; return p; };
  float* x      = (float*)alloc((size_t)N*128*4);     // fp32 master (51.2 MB)
  bf16*  xb     = (bf16*)alloc((size_t)N*128*2);      // bf16 mirror (25.6 MB)
  bf16*  s      = (bf16*)alloc((size_t)N*384*2);      // gathered sums (76.8 MB)
  int*   deg3   = (int*)alloc((size_t)n3*4);
  int*   part   = (int*)alloc((size_t)n3*4);
  int*   rp3    = (int*)alloc((size_t)(n3+1)*4);
  int*   cursor = (int*)alloc((size_t)n3*4);
  int*   pay    = (int*)alloc((size_t)E*4);
  int*   bsum   = (int*)alloc((size_t)nch*4);
  int*   carry  = (int*)alloc((size_t)nch*4);
  float* Wc     = (float*)alloc((size_t)147456*4);
  bf16*  WgiH   = (bf16*)alloc((size_t)147456*2);
  bf16*  WgiL   = (bf16*)alloc((size_t)147456*2);
  bf16*  WghH   = (bf16*)alloc((size_t)49152*2);
  bf16*  WghL   = (bf16*)alloc((size_t)49152*2);
  float* mbp    = (float*)alloc((size_t)1152*4);
  float* pooled = (float*)alloc(64*128*4);
  if(off > ws_size){
    k_diag<<<1,64,0,stream>>>(out, out_size, 1.0e6f + (float)(ws_size>>20));
    return;
  }

  const int tb = 256;
  hipMemsetAsync(deg3, 0, (size_t)n3*4, stream);
  k_wcomb   <<<576, 256, 0, stream>>>(W_ih, msg_W, Wc);
  k_mbp     <<<5, 256, 0, stream>>>(W_ih, msg_b, mbp);
  k_wprep   <<<768, 256, 0, stream>>>(Wc, W_hh, WgiH, WgiL, WghH, WghL);
  k_hist3   <<<(E+tb-1)/tb, tb, 0, stream>>>(dst, edge_type, deg3, E);
  k_scan1   <<<nch, 256, 0, stream>>>(deg3, n3, part, bsum);
  k_scan2   <<<1, 64, 0, stream>>>(bsum, nch, carry);
  k_finalize<<<(n3+tb-1)/tb, tb, 0, stream>>>(part, deg3, carry, n3, rp3, cursor);
  k_fill3   <<<(E+tb-1)/tb, tb, 0, stream>>>(src, dst, edge_type, cursor, pay, E);
  k_embed   <<<N, 128, 0, stream>>>(x_type, x_tok, x_small, type_emb, tok_emb, x, xb, N);

  for(int it=0; it<8; it++){
    k_gather3_b<<<(N+3)/4, 256, 0, stream>>>(xb, rp3, pay, s, N);
    k_mega     <<<(N+63)/64, 256, 0, stream>>>(s, x, xb, WgiH, WgiL, WghH, WghL,
                                               deg3, mbp, b_ih, b_hh, N);
  }
  hipMemsetAsync(pooled, 0, 64*128*4, stream);
  k_pool2<<<dim3(64,32), 128, 0, stream>>>(x, batch, pooled, N);
  k_head <<<64, 128, 0, stream>>>(pooled, batch, N, pW1, pb1, pW2, pb2, out);
}

// Round 8
// 2189.198 us; speedup vs baseline: 1.6675x; 1.0601x over previous
//
#include <hip/hip_runtime.h>
#include <stdint.h>

// GGNN, collapsed + fused iteration (round 8: 32-row blocks for occupancy):
//   s_t[n] = sum_{e:dst=n,type=t} xb[src[e]]     (k_gather3_b, wave per (node,type))
//   k_mega (per 32-row block): gi = s@Wc^T (K=384), gh = x@W_hh^T (K=128),
//     GRU in-register -> x (fp32 master), xb (bf16 mirror). No gi/gh buffers.
// Weights hi/lo bf16 split, packed in MFMA B-frag order, hi/lo adjacent per
// (tile,ks) so each frag-pair is one 2KB contiguous L2-hot region.
// Wave w owns col-tiles {w, w+4, w+8} => feature slice jf in [32w,32w+32)
// across all 3 gates for gi AND gh => GRU needs no data exchange.

typedef __bf16 bf16;
typedef __bf16 v8bf  __attribute__((ext_vector_type(8)));
typedef __bf16 v2bf  __attribute__((ext_vector_type(2)));
typedef float  v16f  __attribute__((ext_vector_type(16)));

#define GI_ELEMS 294912   // 12 tiles * 24 ks * 1024 (hi512+lo512)
#define GH_ELEMS 98304    // 12 tiles *  8 ks * 1024

__device__ __forceinline__ float sigf(float a){ return 1.0f/(1.0f+__expf(-a)); }

__global__ void k_diag(float* out, int n, float v){
  int i = threadIdx.x; if(i<n) out[i] = v;
}

__global__ void k_embed(const int* __restrict__ xtype, const int* __restrict__ xtok,
                        const float* __restrict__ xsmall,
                        const float* __restrict__ temb, const float* __restrict__ kemb,
                        float* __restrict__ x, bf16* __restrict__ xb, int N){
  int n = blockIdx.x; int j = threadIdx.x;
  if(n>=N) return;
  float v;
  if(j<32)       v = temb[xtype[n]*32 + j];
  else if(j<64)  v = kemb[xtok[n]*32 + (j-32)];
  else           v = xsmall[(size_t)n*64 + (j-64)];
  x[(size_t)n*128 + j] = v;
  xb[(size_t)n*128 + j] = (bf16)v;
}

// Wc[o2][K] = sum_k2 W_ih[o2,k2] * msg_W[K>>7][k2][K&127]
__global__ void k_wcomb(const float* __restrict__ W_ih, const float* __restrict__ msg_W,
                        float* __restrict__ Wc){
  int i = blockIdx.x*256 + threadIdx.x;
  if(i >= 147456) return;
  int o2 = i/384, K = i%384;
  const float* wr = W_ih + o2*128;
  const float* mc = msg_W + (K>>7)*16384 + (K&127);
  float acc = 0.f;
  #pragma unroll 4
  for(int k2=0;k2<128;k2++) acc += wr[k2]*mc[k2*128];
  Wc[i] = acc;
}

// mbp[t][o2] = sum_k2 W_ih[o2,k2]*msg_b[t,k2]
__global__ void k_mbp(const float* __restrict__ W_ih, const float* __restrict__ msg_b,
                      float* __restrict__ mbp){
  int i = blockIdx.x*256 + threadIdx.x;
  if(i >= 1152) return;
  int t = i/384, o2 = i%384;
  const float* wr = W_ih + o2*128;
  const float* mb = msg_b + t*128;
  float acc = 0.f;
  #pragma unroll 4
  for(int k2=0;k2<128;k2++) acc += wr[k2]*mb[k2];
  mbp[i] = acc;
}

// Pack weights into MFMA B-frag order, hi/lo adjacent per (tile,ks):
//   gi: Wpack[(tile*24+ks)*1024 + half*512 + lane*8 + j],  n=tile*32+(lane&31),
//       k=ks*16+(lane>>5)*8+j,  from Wc[n*384+k]
//   gh: base GI_ELEMS, (tile*8+ks)*1024 + ..., from W_hh[n*128+k]
__global__ void k_wprep(const float* __restrict__ Wc, const float* __restrict__ W_hh,
                        bf16* __restrict__ Wpack){
  int i = blockIdx.x*256 + threadIdx.x;
  if(i >= GI_ELEMS + GH_ELEMS) return;
  float w;
  int half, lane, j;
  if(i < GI_ELEMS){
    int grp = i/1024, rem = i%1024;          // grp = tile*24+ks
    half = rem/512; int rem2 = rem%512;
    lane = rem2/8; j = rem2%8;
    int tile = grp/24, ks = grp%24;
    int n = tile*32 + (lane&31);
    int k = ks*16 + (lane>>5)*8 + j;
    w = Wc[n*384 + k];
  } else {
    int i2 = i - GI_ELEMS;
    int grp = i2/1024, rem = i2%1024;        // grp = tile*8+ks
    half = rem/512; int rem2 = rem%512;
    lane = rem2/8; j = rem2%8;
    int tile = grp/8, ks = grp%8;
    int n = tile*32 + (lane&31);
    int k = ks*16 + (lane>>5)*8 + j;
    w = W_hh[n*128 + k];
  }
  bf16 h = (bf16)w;
  Wpack[i] = half ? (bf16)(w - (float)h) : h;
}

__global__ void k_hist3(const int* __restrict__ dst, const int* __restrict__ et,
                        int* __restrict__ deg3, int E){
  int e = blockIdx.x*blockDim.x + threadIdx.x;
  if(e<E) atomicAdd(&deg3[dst[e]*3 + et[e]], 1);
}

__global__ void k_scan1(const int* __restrict__ deg, int n, int* __restrict__ part, int* __restrict__ bsum){
  __shared__ int s[256];
  int t = threadIdx.x;
  int base = blockIdx.x*1024 + t*4;
  int v[4]; int sum=0;
  #pragma unroll
  for(int k=0;k<4;k++){ int i=base+k; int d=(i<n)?deg[i]:0; sum+=d; v[k]=sum; }
  s[t]=sum; __syncthreads();
  for(int off=1;off<256;off<<=1){
    int add = (t>=off)? s[t-off] : 0;
    __syncthreads();
    s[t]+=add;
    __syncthreads();
  }
  int excl = (t>0)? s[t-1] : 0;
  #pragma unroll
  for(int k=0;k<4;k++){ int i=base+k; if(i<n) part[i]=v[k]+excl; }
  if(t==255) bsum[blockIdx.x] = s[255];
}

__global__ void k_scan2(const int* __restrict__ bsum, int nb, int* __restrict__ carry){
  if(threadIdx.x==0 && blockIdx.x==0){
    int c=0;
    for(int b=0;b<nb;b++){ carry[b]=c; c+=bsum[b]; }
  }
}

__global__ void k_finalize(const int* __restrict__ part, const int* __restrict__ deg,
                           const int* __restrict__ carry, int n,
                           int* __restrict__ rowptr, int* __restrict__ cursor){
  int i = blockIdx.x*blockDim.x + threadIdx.x;
  if(i>=n) return;
  int incl = part[i] + carry[i>>10];
  rowptr[i+1] = incl;
  cursor[i] = incl - deg[i];
  if(i==0) rowptr[0]=0;
}

__global__ void k_fill3(const int* __restrict__ src, const int* __restrict__ dst,
                        const int* __restrict__ et, int* __restrict__ cursor,
                        int* __restrict__ pay, int E){
  int e = blockIdx.x*blockDim.x + threadIdx.x;
  if(e>=E) return;
  int pos = atomicAdd(&cursor[dst[e]*3 + et[e]], 1);
  pay[pos] = src[e];
}

// gather, wave per (node,type): s[n, t*128+c] = sum typed in-edges xb[src].
// 4-deep pay prefetch -> 4 independent row loads in flight.
__global__ void k_gather3_b(const bf16* __restrict__ xb, const int* __restrict__ rp3,
                            const int* __restrict__ pay, bf16* __restrict__ s, int N3){
  int wid = blockIdx.x*4 + (threadIdx.x>>6);
  if(wid >= N3) return;
  int lane = threadIdx.x & 63;
  int c = lane*2;
  int e0 = rp3[wid], e1 = rp3[wid+1];
  float a = 0.f, b = 0.f;
  int i = e0;
  for(; i+4 <= e1; i+=4){
    int p0 = pay[i], p1 = pay[i+1], p2 = pay[i+2], p3 = pay[i+3];
    v2bf v0 = *(const v2bf*)&xb[(size_t)p0*128 + c];
    v2bf v1 = *(const v2bf*)&xb[(size_t)p1*128 + c];
    v2bf v2 = *(const v2bf*)&xb[(size_t)p2*128 + c];
    v2bf v3 = *(const v2bf*)&xb[(size_t)p3*128 + c];
    a += (float)v0[0]; b += (float)v0[1];
    a += (float)v1[0]; b += (float)v1[1];
    a += (float)v2[0]; b += (float)v2[1];
    a += (float)v3[0]; b += (float)v3[1];
  }
  for(; i < e1; i++){
    v2bf v = *(const v2bf*)&xb[(size_t)pay[i]*128 + c];
    a += (float)v[0]; b += (float)v[1];
  }
  int n = wid/3;
  int t = wid - n*3;
  v2bf o; o[0] = (bf16)a; o[1] = (bf16)b;
  *(v2bf*)&s[(size_t)n*384 + t*128 + c] = o;
}

// Fused gi+gh GEMM + GRU. 32-row block, 256 threads (4 waves).
// Wave w: col-tiles {w, w+4, w+8}; acc: 3 v16f gi + 3 v16f gh = 96 regs.
// A staged once in LDS (single barrier); B direct from L2 packed frag order.
#define SSTR 392   // 384+8 elems: 784B rows, 16B-aligned, 4-way LDS alias (1.58x, acceptable)
#define XSTR 136   // 128+8
__global__ __launch_bounds__(256,2) void k_mega(
    const bf16* __restrict__ s, float* __restrict__ x, bf16* __restrict__ xb,
    const bf16* __restrict__ Wpack,
    const int* __restrict__ deg3, const float* __restrict__ mbp,
    const float* __restrict__ b_ih, const float* __restrict__ b_hh, int M)
{
  __shared__ bf16 Ss[32*SSTR];   // 24.5 KB
  __shared__ bf16 Ax[32*XSTR];   //  8.5 KB
  int tid = threadIdx.x, lane = tid & 63, w = tid >> 6;
  int lrow = lane & 31, q = lane >> 5;
  int row0 = blockIdx.x * 32;

  // stage x tile -> bf16 (32 x 128): 512 chunks, 2/thread
  #pragma unroll
  for(int p=0;p<2;p++){
    int ch = tid + p*256;
    int row = ch>>4, c8 = (ch&15)*8;
    int gr = row0 + row; if(gr >= M) gr = M-1;
    const float* ap = x + (size_t)gr*128 + c8;
    float4 f0 = *(const float4*)ap;
    float4 f1 = *(const float4*)(ap+4);
    v8bf t;
    t[0]=(bf16)f0.x; t[1]=(bf16)f0.y; t[2]=(bf16)f0.z; t[3]=(bf16)f0.w;
    t[4]=(bf16)f1.x; t[5]=(bf16)f1.y; t[6]=(bf16)f1.z; t[7]=(bf16)f1.w;
    *(v8bf*)&Ax[row*XSTR + c8] = t;
  }
  // stage s tile (32 x 384): 1536 chunks, 6/thread
  #pragma unroll
  for(int p=0;p<6;p++){
    int ch = tid + p*256;
    int row = ch/48, c8 = (ch%48)*8;
    int gr = row0 + row; if(gr >= M) gr = M-1;
    *(v8bf*)&Ss[row*SSTR + c8] = *(const v8bf*)(s + (size_t)gr*384 + c8);
  }
  __syncthreads();

  v16f agi[3] = {};
  v16f agh[3] = {};

  // ---- gh: K=128 over Ax ----
  #pragma unroll
  for(int ks=0; ks<8; ks++){
    int kb = ks*16 + q*8;
    v8bf a0 = *(const v8bf*)&Ax[lrow*XSTR + kb];
    #pragma unroll
    for(int ct=0; ct<3; ct++){
      int tile = ct*4 + w;
      size_t fo = GI_ELEMS + (size_t)(tile*8 + ks)*1024 + lane*8;
      v8bf bh = *(const v8bf*)(Wpack + fo);
      v8bf bl = *(const v8bf*)(Wpack + fo + 512);
      agh[ct] = __builtin_amdgcn_mfma_f32_32x32x16_bf16(a0, bh, agh[ct], 0,0,0);
      agh[ct] = __builtin_amdgcn_mfma_f32_32x32x16_bf16(a0, bl, agh[ct], 0,0,0);
    }
  }

  // ---- gi: K=384 over Ss ----
  #pragma unroll
  for(int ks=0; ks<24; ks++){
    int kb = ks*16 + q*8;
    v8bf a0 = *(const v8bf*)&Ss[lrow*SSTR + kb];
    #pragma unroll
    for(int ct=0; ct<3; ct++){
      int tile = ct*4 + w;
      size_t fo = (size_t)(tile*24 + ks)*1024 + lane*8;
      v8bf bh = *(const v8bf*)(Wpack + fo);
      v8bf bl = *(const v8bf*)(Wpack + fo + 512);
      agi[ct] = __builtin_amdgcn_mfma_f32_32x32x16_bf16(a0, bh, agi[ct], 0,0,0);
      agi[ct] = __builtin_amdgcn_mfma_f32_32x32x16_bf16(a0, bl, agi[ct], 0,0,0);
    }
  }

  // ---- GRU epilogue, in-register. jf = this lane's feature. ----
  int jf = w*32 + lrow;
  float bi0 = b_ih[jf],     bh0 = b_hh[jf];
  float bi1 = b_ih[128+jf], bh1 = b_hh[128+jf];
  float bi2 = b_ih[256+jf], bh2 = b_hh[256+jf];
  float mb[3][3];
  #pragma unroll
  for(int t=0;t<3;t++){
    mb[t][0] = mbp[t*384 + jf];
    mb[t][1] = mbp[t*384 + 128 + jf];
    mb[t][2] = mbp[t*384 + 256 + jf];
  }
  int rq4 = 4*q;
  #pragma unroll
  for(int r=0;r<16;r++){
    int gr = row0 + (r&3) + 8*(r>>2) + rq4;
    if(gr >= M) continue;
    const int* dq = &deg3[gr*3];
    float d0 = (float)dq[0], d1 = (float)dq[1], d2 = (float)dq[2];
    float ir  = agi[0][r] + bi0 + d0*mb[0][0] + d1*mb[1][0] + d2*mb[2][0];
    float iz  = agi[1][r] + bi1 + d0*mb[0][1] + d1*mb[1][1] + d2*mb[2][1];
    float in_ = agi[2][r] + bi2 + d0*mb[0][2] + d1*mb[1][2] + d2*mb[2][2];
    float hr  = agh[0][r] + bh0;
    float hz  = agh[1][r] + bh1;
    float hn  = agh[2][r] + bh2;
    float rg = sigf(ir + hr);
    float zg = sigf(iz + hz);
    float nn = tanhf(in_ + rg*hn);
    size_t xi = (size_t)gr*128 + jf;
    float xo = x[xi];
    float xv = (1.f - zg)*nn + zg*xo;
    x[xi] = xv;
    xb[xi] = (bf16)xv;
  }
}

__device__ __forceinline__ int lb_batch(const int* __restrict__ batch, int N, int g){
  int lo=0, hi=N;
  while(lo<hi){ int mid=(lo+hi)>>1; if(batch[mid]<g) lo=mid+1; else hi=mid; }
  return lo;
}

__global__ void k_pool2(const float* __restrict__ x, const int* __restrict__ batch,
                        float* __restrict__ pooled, int N){
  int g = blockIdx.x, slice = blockIdx.y;
  int j = threadIdx.x;
  int lo = lb_batch(batch,N,g), hi = lb_batch(batch,N,g+1);
  float acc = 0.f;
  for(int r=lo+slice; r<hi; r+=32) acc += x[(size_t)r*128 + j];
  atomicAdd(&pooled[g*128+j], acc);
}

__global__ void k_head(const float* __restrict__ pooled, const int* __restrict__ batch, int N,
                       const float* __restrict__ W1, const float* __restrict__ b1,
                       const float* __restrict__ W2, const float* __restrict__ b2,
                       float* __restrict__ out){
  int g = blockIdx.x; int j = threadIdx.x;
  __shared__ float p[128];
  __shared__ float red[128];
  int lo = lb_batch(batch,N,g), hi = lb_batch(batch,N,g+1);
  float c = (float)(hi-lo); if(c < 1.f) c = 1.f;
  p[j] = pooled[g*128+j] / c;
  __syncthreads();
  float acc = b1[j];
  #pragma unroll 4
  for(int i=0;i<128;i++) acc += W1[j*128+i]*p[i];
  float v = (acc>0.f?acc:0.f) * W2[j];
  red[j] = v; __syncthreads();
  for(int s=64;s>0;s>>=1){ if(j<s) red[j]+=red[j+s]; __syncthreads(); }
  if(j==0) out[g] = red[0] + b2[0];
}

extern "C" void kernel_launch(void* const* d_in, const int* in_sizes, int n_in,
                              void* d_out, int out_size, void* d_ws, size_t ws_size,
                              hipStream_t stream){
  const int*   x_type    = (const int*)d_in[0];
  const int*   x_tok     = (const int*)d_in[1];
  const float* x_small   = (const float*)d_in[2];
  const int*   edge_index= (const int*)d_in[3];
  const int*   edge_type = (const int*)d_in[4];
  const int*   batch     = (const int*)d_in[5];
  const float* type_emb  = (const float*)d_in[6];
  const float* tok_emb   = (const float*)d_in[7];
  const float* msg_W     = (const float*)d_in[8];
  const float* msg_b     = (const float*)d_in[9];
  const float* W_ih      = (const float*)d_in[10];
  const float* W_hh      = (const float*)d_in[11];
  const float* b_ih      = (const float*)d_in[12];
  const float* b_hh      = (const float*)d_in[13];
  const float* pW1       = (const float*)d_in[14];
  const float* pb1       = (const float*)d_in[15];
  const float* pW2       = (const float*)d_in[16];
  const float* pb2       = (const float*)d_in[17];
  float* out = (float*)d_out;

  int N = in_sizes[0];
  int E = in_sizes[3]/2;
  const int* src = edge_index;
  const int* dst = edge_index + E;
  int n3 = 3*N;
  int nch = (n3+1023)/1024;

  char* w = (char*)d_ws;
  size_t off = 0;
  auto alloc = [&](size_t bytes)->char*{ char* p = w + off; off += (bytes + 511) & ~511ull; return p; };
  float* x      = (float*)alloc((size_t)N*128*4);     // fp32 master (51.2 MB)
  bf16*  xb     = (bf16*)alloc((size_t)N*128*2);      // bf16 mirror (25.6 MB)
  bf16*  s      = (bf16*)alloc((size_t)N*384*2);      // gathered sums (76.8 MB)
  int*   deg3   = (int*)alloc((size_t)n3*4);
  int*   part   = (int*)alloc((size_t)n3*4);
  int*   rp3    = (int*)alloc((size_t)(n3+1)*4);
  int*   cursor = (int*)alloc((size_t)n3*4);
  int*   pay    = (int*)alloc((size_t)E*4);
  int*   bsum   = (int*)alloc((size_t)nch*4);
  int*   carry  = (int*)alloc((size_t)nch*4);
  float* Wc     = (float*)alloc((size_t)147456*4);
  bf16*  Wpack  = (bf16*)alloc((size_t)(GI_ELEMS+GH_ELEMS)*2);
  float* mbp    = (float*)alloc((size_t)1152*4);
  float* pooled = (float*)alloc(64*128*4);
  if(off > ws_size){
    k_diag<<<1,64,0,stream>>>(out, out_size, 1.0e6f + (float)(ws_size>>20));
    return;
  }

  const int tb = 256;
  hipMemsetAsync(deg3, 0, (size_t)n3*4, stream);
  k_wcomb   <<<576, 256, 0, stream>>>(W_ih, msg_W, Wc);
  k_mbp     <<<5, 256, 0, stream>>>(W_ih, msg_b, mbp);
  k_wprep   <<<(GI_ELEMS+GH_ELEMS+255)/256, 256, 0, stream>>>(Wc, W_hh, Wpack);
  k_hist3   <<<(E+tb-1)/tb, tb, 0, stream>>>(dst, edge_type, deg3, E);
  k_scan1   <<<nch, 256, 0, stream>>>(deg3, n3, part, bsum);
  k_scan2   <<<1, 64, 0, stream>>>(bsum, nch, carry);
  k_finalize<<<(n3+tb-1)/tb, tb, 0, stream>>>(part, deg3, carry, n3, rp3, cursor);
  k_fill3   <<<(E+tb-1)/tb, tb, 0, stream>>>(src, dst, edge_type, cursor, pay, E);
  k_embed   <<<N, 128, 0, stream>>>(x_type, x_tok, x_small, type_emb, tok_emb, x, xb, N);

  for(int it=0; it<8; it++){
    k_gather3_b<<<(n3+3)/4, 256, 0, stream>>>(xb, rp3, pay, s, n3);
    k_mega     <<<(N+31)/32, 256, 0, stream>>>(s, x, xb, Wpack, deg3, mbp, b_ih, b_hh, N);
  }
  hipMemsetAsync(pooled, 0, 64*128*4, stream);
  k_pool2<<<dim3(64,32), 128, 0, stream>>>(x, batch, pooled, N);
  k_head <<<64, 128, 0, stream>>>(pooled, batch, N, pW1, pb1, pW2, pb2, out);
}

// Round 9
// 2183.389 us; speedup vs baseline: 1.6719x; 1.0027x over previous
//
#include <hip/hip_runtime.h>
#include <stdint.h>

// GGNN round 9: collapsed + single fused iteration kernel k_giga.
//   Per 32-row block: gather typed sums from xb_old directly into LDS (f16),
//   gi = s@Wc^T (K=384), gh = x@W_hh^T (K=128), GRU in-register -> x, xb_new.
//   xb ping-pong buffers break the cross-block read/write race.
// Iters 0..6: f16 single weights (mfma_f32_32x32x16_f16), iter 7: bf16 hi/lo
// (~16-bit mantissa) so final-iteration gate error stays at round-8 quality.

typedef __bf16 bf16;
typedef _Float16 f16;
typedef __bf16   v8bf __attribute__((ext_vector_type(8)));
typedef _Float16 v8hf __attribute__((ext_vector_type(8)));
typedef _Float16 v2hf __attribute__((ext_vector_type(2)));
typedef float    v16f __attribute__((ext_vector_type(16)));

#define GI_B 294912   // bf16 hilo: 12 tiles * 24 ks * 1024 (hi512+lo512)
#define GH_B 98304    // 12 * 8 * 1024
#define GI_F 147456   // f16 single: 12 * 24 * 512
#define GH_F 49152    // 12 * 8 * 512

__device__ __forceinline__ float sigf(float a){ return 1.0f/(1.0f+__expf(-a)); }

__global__ void k_diag(float* out, int n, float v){
  int i = threadIdx.x; if(i<n) out[i] = v;
}

__global__ void k_embed(const int* __restrict__ xtype, const int* __restrict__ xtok,
                        const float* __restrict__ xsmall,
                        const float* __restrict__ temb, const float* __restrict__ kemb,
                        float* __restrict__ x, f16* __restrict__ xb, int N){
  int n = blockIdx.x; int j = threadIdx.x;
  if(n>=N) return;
  float v;
  if(j<32)       v = temb[xtype[n]*32 + j];
  else if(j<64)  v = kemb[xtok[n]*32 + (j-32)];
  else           v = xsmall[(size_t)n*64 + (j-64)];
  x[(size_t)n*128 + j] = v;
  xb[(size_t)n*128 + j] = (f16)v;
}

// Wc[o2][K] = sum_k2 W_ih[o2,k2] * msg_W[K>>7][k2][K&127]
__global__ void k_wcomb(const float* __restrict__ W_ih, const float* __restrict__ msg_W,
                        float* __restrict__ Wc){
  int i = blockIdx.x*256 + threadIdx.x;
  if(i >= 147456) return;
  int o2 = i/384, K = i%384;
  const float* wr = W_ih + o2*128;
  const float* mc = msg_W + (K>>7)*16384 + (K&127);
  float acc = 0.f;
  #pragma unroll 4
  for(int k2=0;k2<128;k2++) acc += wr[k2]*mc[k2*128];
  Wc[i] = acc;
}

// mbp[t][o2] = sum_k2 W_ih[o2,k2]*msg_b[t,k2]
__global__ void k_mbp(const float* __restrict__ W_ih, const float* __restrict__ msg_b,
                      float* __restrict__ mbp){
  int i = blockIdx.x*256 + threadIdx.x;
  if(i >= 1152) return;
  int t = i/384, o2 = i%384;
  const float* wr = W_ih + o2*128;
  const float* mb = msg_b + t*128;
  float acc = 0.f;
  #pragma unroll 4
  for(int k2=0;k2<128;k2++) acc += wr[k2]*mb[k2];
  mbp[i] = acc;
}

// Pack weights: WpB = bf16 hi/lo (round-8 layout), WpF = f16 single.
// frag elem: n = tile*32 + (lane&31), k = ks*16 + (lane>>5)*8 + j
__global__ void k_wprep(const float* __restrict__ Wc, const float* __restrict__ W_hh,
                        bf16* __restrict__ WpB, f16* __restrict__ WpF){
  int i = blockIdx.x*256 + threadIdx.x;
  if(i < GI_B + GH_B){
    float w; int half, lane, j;
    if(i < GI_B){
      int grp = i/1024, rem = i%1024;
      half = rem/512; int rem2 = rem%512;
      lane = rem2/8; j = rem2%8;
      int tile = grp/24, ks = grp%24;
      int n = tile*32 + (lane&31);
      int k = ks*16 + (lane>>5)*8 + j;
      w = Wc[n*384 + k];
    } else {
      int i2 = i - GI_B;
      int grp = i2/1024, rem = i2%1024;
      half = rem/512; int rem2 = rem%512;
      lane = rem2/8; j = rem2%8;
      int tile = grp/8, ks = grp%8;
      int n = tile*32 + (lane&31);
      int k = ks*16 + (lane>>5)*8 + j;
      w = W_hh[n*128 + k];
    }
    bf16 h = (bf16)w;
    WpB[i] = half ? (bf16)(w - (float)h) : h;
  }
  if(i < GI_F + GH_F){
    float w; int lane, j;
    if(i < GI_F){
      int grp = i/512, rem = i%512;
      lane = rem/8; j = rem%8;
      int tile = grp/24, ks = grp%24;
      int n = tile*32 + (lane&31);
      int k = ks*16 + (lane>>5)*8 + j;
      w = Wc[n*384 + k];
    } else {
      int i2 = i - GI_F;
      int grp = i2/512, rem = i2%512;
      lane = rem/8; j = rem%8;
      int tile = grp/8, ks = grp%8;
      int n = tile*32 + (lane&31);
      int k = ks*16 + (lane>>5)*8 + j;
      w = W_hh[n*128 + k];
    }
    WpF[i] = (f16)w;
  }
}

__global__ void k_hist3(const int* __restrict__ dst, const int* __restrict__ et,
                        int* __restrict__ deg3, int E){
  int e = blockIdx.x*blockDim.x + threadIdx.x;
  if(e<E) atomicAdd(&deg3[dst[e]*3 + et[e]], 1);
}

__global__ void k_scan1(const int* __restrict__ deg, int n, int* __restrict__ part, int* __restrict__ bsum){
  __shared__ int s[256];
  int t = threadIdx.x;
  int base = blockIdx.x*1024 + t*4;
  int v[4]; int sum=0;
  #pragma unroll
  for(int k=0;k<4;k++){ int i=base+k; int d=(i<n)?deg[i]:0; sum+=d; v[k]=sum; }
  s[t]=sum; __syncthreads();
  for(int off=1;off<256;off<<=1){
    int add = (t>=off)? s[t-off] : 0;
    __syncthreads();
    s[t]+=add;
    __syncthreads();
  }
  int excl = (t>0)? s[t-1] : 0;
  #pragma unroll
  for(int k=0;k<4;k++){ int i=base+k; if(i<n) part[i]=v[k]+excl; }
  if(t==255) bsum[blockIdx.x] = s[255];
}

__global__ void k_scan2(const int* __restrict__ bsum, int nb, int* __restrict__ carry){
  if(threadIdx.x==0 && blockIdx.x==0){
    int c=0;
    for(int b=0;b<nb;b++){ carry[b]=c; c+=bsum[b]; }
  }
}

__global__ void k_finalize(const int* __restrict__ part, const int* __restrict__ deg,
                           const int* __restrict__ carry, int n,
                           int* __restrict__ rowptr, int* __restrict__ cursor){
  int i = blockIdx.x*blockDim.x + threadIdx.x;
  if(i>=n) return;
  int incl = part[i] + carry[i>>10];
  rowptr[i+1] = incl;
  cursor[i] = incl - deg[i];
  if(i==0) rowptr[0]=0;
}

__global__ void k_fill3(const int* __restrict__ src, const int* __restrict__ dst,
                        const int* __restrict__ et, int* __restrict__ cursor,
                        int* __restrict__ pay, int E){
  int e = blockIdx.x*blockDim.x + threadIdx.x;
  if(e>=E) return;
  int pos = atomicAdd(&cursor[dst[e]*3 + et[e]], 1);
  pay[pos] = src[e];
}

// Fused gather + gi/gh GEMM + GRU. 32 rows/block, 256 threads (4 waves).
// Phase A: stage x rows (dtype D) + gather typed sums from xb_old into LDS.
// Phase B: wave w col-tiles {w,w+4,w+8}: gi K=384, gh K=128 (MODE0 f16 single,
// MODE1 bf16 hi/lo). Phase C: GRU in-register -> x (fp32), xb_new (f16).
#define SSTR 392   // 384+8
#define XSTR 136   // 128+8
template<int MODE>
__global__ __launch_bounds__(256,2) void k_giga(
    const f16* __restrict__ xb_old, float* __restrict__ x, f16* __restrict__ xb_new,
    const f16* __restrict__ WpF, const bf16* __restrict__ WpB,
    const int* __restrict__ rp3, const int* __restrict__ pay,
    const int* __restrict__ deg3, const float* __restrict__ mbp,
    const float* __restrict__ b_ih, const float* __restrict__ b_hh, int M)
{
  __shared__ unsigned short Ss_[32*SSTR];   // 24.5 KB, dtype D
  __shared__ unsigned short Ax_[32*XSTR];   //  8.5 KB, dtype D
  int tid = threadIdx.x, lane = tid & 63, w = tid >> 6;
  int lrow = lane & 31, q = lane >> 5;
  int row0 = blockIdx.x * 32;

  // --- Phase A1: stage x rows -> Ax (dtype D) ---
  #pragma unroll
  for(int p=0;p<2;p++){
    int ch = tid + p*256;
    int row = ch>>4, c8 = (ch&15)*8;
    int gr = row0 + row; if(gr >= M) gr = M-1;
    const float* ap = x + (size_t)gr*128 + c8;
    float4 f0 = *(const float4*)ap;
    float4 f1 = *(const float4*)(ap+4);
    if(MODE==0){
      v8hf t;
      t[0]=(f16)f0.x; t[1]=(f16)f0.y; t[2]=(f16)f0.z; t[3]=(f16)f0.w;
      t[4]=(f16)f1.x; t[5]=(f16)f1.y; t[6]=(f16)f1.z; t[7]=(f16)f1.w;
      *(v8hf*)&Ax_[row*XSTR + c8] = t;
    } else {
      v8bf t;
      t[0]=(bf16)f0.x; t[1]=(bf16)f0.y; t[2]=(bf16)f0.z; t[3]=(bf16)f0.w;
      t[4]=(bf16)f1.x; t[5]=(bf16)f1.y; t[6]=(bf16)f1.z; t[7]=(bf16)f1.w;
      *(v8bf*)&Ax_[row*XSTR + c8] = t;
    }
  }

  // --- Phase A2: gather typed sums -> Ss. Wave w owns rows [w*8, w*8+8). ---
  {
    int c = lane*2;
    #pragma unroll 2
    for(int rr=0; rr<8; rr++){
      int row = w*8 + rr;
      int gr = row0 + row;
      #pragma unroll
      for(int t=0; t<3; t++){
        float a=0.f, b=0.f;
        if(gr < M){
          int bin = gr*3 + t;
          int i = rp3[bin], e1 = rp3[bin+1];
          for(; i+4<=e1; i+=4){
            int p0=pay[i], p1=pay[i+1], p2=pay[i+2], p3=pay[i+3];
            v2hf u0 = *(const v2hf*)&xb_old[(size_t)p0*128 + c];
            v2hf u1 = *(const v2hf*)&xb_old[(size_t)p1*128 + c];
            v2hf u2 = *(const v2hf*)&xb_old[(size_t)p2*128 + c];
            v2hf u3 = *(const v2hf*)&xb_old[(size_t)p3*128 + c];
            a += (float)u0[0]+(float)u1[0]+(float)u2[0]+(float)u3[0];
            b += (float)u0[1]+(float)u1[1]+(float)u2[1]+(float)u3[1];
          }
          for(; i<e1; i++){
            v2hf u = *(const v2hf*)&xb_old[(size_t)pay[i]*128 + c];
            a += (float)u[0]; b += (float)u[1];
          }
        }
        int o = row*SSTR + t*128 + c;
        if(MODE==0){
          v2hf v; v[0]=(f16)a; v[1]=(f16)b;
          *(v2hf*)&Ss_[o] = v;
        } else {
          bf16* sp = (bf16*)Ss_;
          sp[o] = (bf16)a; sp[o+1] = (bf16)b;
        }
      }
    }
  }
  __syncthreads();

  // --- Phase B: MFMAs ---
  v16f agi[3] = {};
  v16f agh[3] = {};

  if(MODE==0){
    const f16* Ss = (const f16*)Ss_;
    const f16* Ax = (const f16*)Ax_;
    #pragma unroll
    for(int ks=0; ks<8; ks++){
      int kb = ks*16 + q*8;
      v8hf a0 = *(const v8hf*)&Ax[lrow*XSTR + kb];
      #pragma unroll
      for(int ct=0; ct<3; ct++){
        int tile = ct*4 + w;
        v8hf bh = *(const v8hf*)(WpF + GI_F + (size_t)(tile*8 + ks)*512 + lane*8);
        agh[ct] = __builtin_amdgcn_mfma_f32_32x32x16_f16(a0, bh, agh[ct], 0,0,0);
      }
    }
    #pragma unroll
    for(int ks=0; ks<24; ks++){
      int kb = ks*16 + q*8;
      v8hf a0 = *(const v8hf*)&Ss[lrow*SSTR + kb];
      #pragma unroll
      for(int ct=0; ct<3; ct++){
        int tile = ct*4 + w;
        v8hf bh = *(const v8hf*)(WpF + (size_t)(tile*24 + ks)*512 + lane*8);
        agi[ct] = __builtin_amdgcn_mfma_f32_32x32x16_f16(a0, bh, agi[ct], 0,0,0);
      }
    }
  } else {
    const bf16* Ss = (const bf16*)Ss_;
    const bf16* Ax = (const bf16*)Ax_;
    #pragma unroll
    for(int ks=0; ks<8; ks++){
      int kb = ks*16 + q*8;
      v8bf a0 = *(const v8bf*)&Ax[lrow*XSTR + kb];
      #pragma unroll
      for(int ct=0; ct<3; ct++){
        int tile = ct*4 + w;
        size_t fo = GI_B + (size_t)(tile*8 + ks)*1024 + lane*8;
        v8bf bh = *(const v8bf*)(WpB + fo);
        v8bf bl = *(const v8bf*)(WpB + fo + 512);
        agh[ct] = __builtin_amdgcn_mfma_f32_32x32x16_bf16(a0, bh, agh[ct], 0,0,0);
        agh[ct] = __builtin_amdgcn_mfma_f32_32x32x16_bf16(a0, bl, agh[ct], 0,0,0);
      }
    }
    #pragma unroll
    for(int ks=0; ks<24; ks++){
      int kb = ks*16 + q*8;
      v8bf a0 = *(const v8bf*)&Ss[lrow*SSTR + kb];
      #pragma unroll
      for(int ct=0; ct<3; ct++){
        int tile = ct*4 + w;
        size_t fo = (size_t)(tile*24 + ks)*1024 + lane*8;
        v8bf bh = *(const v8bf*)(WpB + fo);
        v8bf bl = *(const v8bf*)(WpB + fo + 512);
        agi[ct] = __builtin_amdgcn_mfma_f32_32x32x16_bf16(a0, bh, agi[ct], 0,0,0);
        agi[ct] = __builtin_amdgcn_mfma_f32_32x32x16_bf16(a0, bl, agi[ct], 0,0,0);
      }
    }
  }

  // --- Phase C: GRU epilogue. jf = this lane's feature. ---
  int jf = w*32 + lrow;
  float bi0 = b_ih[jf],     bh0 = b_hh[jf];
  float bi1 = b_ih[128+jf], bh1 = b_hh[128+jf];
  float bi2 = b_ih[256+jf], bh2 = b_hh[256+jf];
  float mb[3][3];
  #pragma unroll
  for(int t=0;t<3;t++){
    mb[t][0] = mbp[t*384 + jf];
    mb[t][1] = mbp[t*384 + 128 + jf];
    mb[t][2] = mbp[t*384 + 256 + jf];
  }
  int rq4 = 4*q;
  #pragma unroll
  for(int r=0;r<16;r++){
    int gr = row0 + (r&3) + 8*(r>>2) + rq4;
    if(gr >= M) continue;
    const int* dq = &deg3[gr*3];
    float d0 = (float)dq[0], d1 = (float)dq[1], d2 = (float)dq[2];
    float ir  = agi[0][r] + bi0 + d0*mb[0][0] + d1*mb[1][0] + d2*mb[2][0];
    float iz  = agi[1][r] + bi1 + d0*mb[0][1] + d1*mb[1][1] + d2*mb[2][1];
    float in_ = agi[2][r] + bi2 + d0*mb[0][2] + d1*mb[1][2] + d2*mb[2][2];
    float hr  = agh[0][r] + bh0;
    float hz  = agh[1][r] + bh1;
    float hn  = agh[2][r] + bh2;
    float rg = sigf(ir + hr);
    float zg = sigf(iz + hz);
    float nn = tanhf(in_ + rg*hn);
    size_t xi = (size_t)gr*128 + jf;
    float xo = x[xi];
    float xv = (1.f - zg)*nn + zg*xo;
    x[xi] = xv;
    xb_new[xi] = (f16)xv;
  }
}

__device__ __forceinline__ int lb_batch(const int* __restrict__ batch, int N, int g){
  int lo=0, hi=N;
  while(lo<hi){ int mid=(lo+hi)>>1; if(batch[mid]<g) lo=mid+1; else hi=mid; }
  return lo;
}

__global__ void k_pool2(const float* __restrict__ x, const int* __restrict__ batch,
                        float* __restrict__ pooled, int N){
  int g = blockIdx.x, slice = blockIdx.y;
  int j = threadIdx.x;
  int lo = lb_batch(batch,N,g), hi = lb_batch(batch,N,g+1);
  float acc = 0.f;
  for(int r=lo+slice; r<hi; r+=32) acc += x[(size_t)r*128 + j];
  atomicAdd(&pooled[g*128+j], acc);
}

__global__ void k_head(const float* __restrict__ pooled, const int* __restrict__ batch, int N,
                       const float* __restrict__ W1, const float* __restrict__ b1,
                       const float* __restrict__ W2, const float* __restrict__ b2,
                       float* __restrict__ out){
  int g = blockIdx.x; int j = threadIdx.x;
  __shared__ float p[128];
  __shared__ float red[128];
  int lo = lb_batch(batch,N,g), hi = lb_batch(batch,N,g+1);
  float c = (float)(hi-lo); if(c < 1.f) c = 1.f;
  p[j] = pooled[g*128+j] / c;
  __syncthreads();
  float acc = b1[j];
  #pragma unroll 4
  for(int i=0;i<128;i++) acc += W1[j*128+i]*p[i];
  float v = (acc>0.f?acc:0.f) * W2[j];
  red[j] = v; __syncthreads();
  for(int s=64;s>0;s>>=1){ if(j<s) red[j]+=red[j+s]; __syncthreads(); }
  if(j==0) out[g] = red[0] + b2[0];
}

extern "C" void kernel_launch(void* const* d_in, const int* in_sizes, int n_in,
                              void* d_out, int out_size, void* d_ws, size_t ws_size,
                              hipStream_t stream){
  const int*   x_type    = (const int*)d_in[0];
  const int*   x_tok     = (const int*)d_in[1];
  const float* x_small   = (const float*)d_in[2];
  const int*   edge_index= (const int*)d_in[3];
  const int*   edge_type = (const int*)d_in[4];
  const int*   batch     = (const int*)d_in[5];
  const float* type_emb  = (const float*)d_in[6];
  const float* tok_emb   = (const float*)d_in[7];
  const float* msg_W     = (const float*)d_in[8];
  const float* msg_b     = (const float*)d_in[9];
  const float* W_ih      = (const float*)d_in[10];
  const float* W_hh      = (const float*)d_in[11];
  const float* b_ih      = (const float*)d_in[12];
  const float* b_hh      = (const float*)d_in[13];
  const float* pW1       = (const float*)d_in[14];
  const float* pb1       = (const float*)d_in[15];
  const float* pW2       = (const float*)d_in[16];
  const float* pb2       = (const float*)d_in[17];
  float* out = (float*)d_out;

  int N = in_sizes[0];
  int E = in_sizes[3]/2;
  const int* src = edge_index;
  const int* dst = edge_index + E;
  int n3 = 3*N;
  int nch = (n3+1023)/1024;

  char* w = (char*)d_ws;
  size_t off = 0;
  auto alloc = [&](size_t bytes)->char*{ char* p = w + off; off += (bytes + 511) & ~511ull; return p; };
  float* x      = (float*)alloc((size_t)N*128*4);     // fp32 master (51.2 MB)
  f16*   xb0    = (f16*)alloc((size_t)N*128*2);       // ping (25.6 MB)
  f16*   xb1    = (f16*)alloc((size_t)N*128*2);       // pong (25.6 MB)
  int*   deg3   = (int*)alloc((size_t)n3*4);
  int*   part   = (int*)alloc((size_t)n3*4);
  int*   rp3    = (int*)alloc((size_t)(n3+1)*4);
  int*   cursor = (int*)alloc((size_t)n3*4);
  int*   pay    = (int*)alloc((size_t)E*4);
  int*   bsum   = (int*)alloc((size_t)nch*4);
  int*   carry  = (int*)alloc((size_t)nch*4);
  float* Wc     = (float*)alloc((size_t)147456*4);
  bf16*  WpB    = (bf16*)alloc((size_t)(GI_B+GH_B)*2);
  f16*   WpF    = (f16*)alloc((size_t)(GI_F+GH_F)*2);
  float* mbp    = (float*)alloc((size_t)1152*4);
  float* pooled = (float*)alloc(64*128*4);
  if(off > ws_size){
    k_diag<<<1,64,0,stream>>>(out, out_size, 1.0e6f + (float)(ws_size>>20));
    return;
  }

  const int tb = 256;
  hipMemsetAsync(deg3, 0, (size_t)n3*4, stream);
  k_wcomb   <<<576, 256, 0, stream>>>(W_ih, msg_W, Wc);
  k_mbp     <<<5, 256, 0, stream>>>(W_ih, msg_b, mbp);
  k_wprep   <<<(GI_B+GH_B+255)/256, 256, 0, stream>>>(Wc, W_hh, WpB, WpF);
  k_hist3   <<<(E+tb-1)/tb, tb, 0, stream>>>(dst, edge_type, deg3, E);
  k_scan1   <<<nch, 256, 0, stream>>>(deg3, n3, part, bsum);
  k_scan2   <<<1, 64, 0, stream>>>(bsum, nch, carry);
  k_finalize<<<(n3+tb-1)/tb, tb, 0, stream>>>(part, deg3, carry, n3, rp3, cursor);
  k_fill3   <<<(E+tb-1)/tb, tb, 0, stream>>>(src, dst, edge_type, cursor, pay, E);
  k_embed   <<<N, 128, 0, stream>>>(x_type, x_tok, x_small, type_emb, tok_emb, x, xb0, N);

  int nblk = (N+31)/32;
  for(int it=0; it<8; it++){
    f16* xin  = (it&1) ? xb1 : xb0;
    f16* xout = (it&1) ? xb0 : xb1;
    if(it < 7)
      k_giga<0><<<nblk, 256, 0, stream>>>(xin, x, xout, WpF, WpB, rp3, pay,
                                          deg3, mbp, b_ih, b_hh, N);
    else
      k_giga<1><<<nblk, 256, 0, stream>>>(xin, x, xout, WpF, WpB, rp3, pay,
                                          deg3, mbp, b_ih, b_hh, N);
  }
  hipMemsetAsync(pooled, 0, 64*128*4, stream);
  k_pool2<<<dim3(64,32), 128, 0, stream>>>(x, batch, pooled, N);
  k_head <<<64, 128, 0, stream>>>(pooled, batch, N, pW1, pb1, pW2, pb2, out);
}

// Round 10
// 2018.718 us; speedup vs baseline: 1.8083x; 1.0816x over previous
//
#include <hip/hip_runtime.h>
#include <stdint.h>

// GGNN round 10: f16 master state (no fp32 x), split gather + f16 MFMA iteration.
//   s_t[n] = sum_{e:dst=n,type=t} xb[src[e]]        (k_gather3_b, wave/(node,type))
//   k_mega2 (32-row block): gi = s@Wc^T (K=384, f16), gh = xb@W_hh^T (K=128, f16),
//     GRU in-register (x_old read from the staged LDS tile) -> xb_new (f16).
//   xb ping-pong breaks the cross-block gather/write race.
// All 8 iters f16 single weights: round-8 (bf16 hi/lo) and round-9 (f16) produced
// IDENTICAL absmax 6.1e-5 => weight mantissa is not the error driver.

typedef _Float16 f16;
typedef _Float16 v8hf __attribute__((ext_vector_type(8)));
typedef _Float16 v2hf __attribute__((ext_vector_type(2)));
typedef float    v16f __attribute__((ext_vector_type(16)));

#define GI_F 147456   // 12 tiles * 24 ks * 512
#define GH_F 49152    // 12 tiles *  8 ks * 512

__device__ __forceinline__ float sigf(float a){ return 1.0f/(1.0f+__expf(-a)); }

__global__ void k_diag(float* out, int n, float v){
  int i = threadIdx.x; if(i<n) out[i] = v;
}

__global__ void k_embed(const int* __restrict__ xtype, const int* __restrict__ xtok,
                        const float* __restrict__ xsmall,
                        const float* __restrict__ temb, const float* __restrict__ kemb,
                        f16* __restrict__ xb, int N){
  int n = blockIdx.x; int j = threadIdx.x;
  if(n>=N) return;
  float v;
  if(j<32)       v = temb[xtype[n]*32 + j];
  else if(j<64)  v = kemb[xtok[n]*32 + (j-32)];
  else           v = xsmall[(size_t)n*64 + (j-64)];
  xb[(size_t)n*128 + j] = (f16)v;
}

// Wc[o2][K] = sum_k2 W_ih[o2,k2] * msg_W[K>>7][k2][K&127]
__global__ void k_wcomb(const float* __restrict__ W_ih, const float* __restrict__ msg_W,
                        float* __restrict__ Wc){
  int i = blockIdx.x*256 + threadIdx.x;
  if(i >= 147456) return;
  int o2 = i/384, K = i%384;
  const float* wr = W_ih + o2*128;
  const float* mc = msg_W + (K>>7)*16384 + (K&127);
  float acc = 0.f;
  #pragma unroll 4
  for(int k2=0;k2<128;k2++) acc += wr[k2]*mc[k2*128];
  Wc[i] = acc;
}

// mbp[t][o2] = sum_k2 W_ih[o2,k2]*msg_b[t,k2]
__global__ void k_mbp(const float* __restrict__ W_ih, const float* __restrict__ msg_b,
                      float* __restrict__ mbp){
  int i = blockIdx.x*256 + threadIdx.x;
  if(i >= 1152) return;
  int t = i/384, o2 = i%384;
  const float* wr = W_ih + o2*128;
  const float* mb = msg_b + t*128;
  float acc = 0.f;
  #pragma unroll 4
  for(int k2=0;k2<128;k2++) acc += wr[k2]*mb[k2];
  mbp[i] = acc;
}

// Pack weights f16, MFMA B-frag order: n = tile*32+(lane&31), k = ks*16+(lane>>5)*8+j
__global__ void k_wprep(const float* __restrict__ Wc, const float* __restrict__ W_hh,
                        f16* __restrict__ WpF){
  int i = blockIdx.x*256 + threadIdx.x;
  if(i >= GI_F + GH_F) return;
  float w; int lane, j;
  if(i < GI_F){
    int grp = i/512, rem = i%512;
    lane = rem/8; j = rem%8;
    int tile = grp/24, ks = grp%24;
    int n = tile*32 + (lane&31);
    int k = ks*16 + (lane>>5)*8 + j;
    w = Wc[n*384 + k];
  } else {
    int i2 = i - GI_F;
    int grp = i2/512, rem = i2%512;
    lane = rem/8; j = rem%8;
    int tile = grp/8, ks = grp%8;
    int n = tile*32 + (lane&31);
    int k = ks*16 + (lane>>5)*8 + j;
    w = W_hh[n*128 + k];
  }
  WpF[i] = (f16)w;
}

__global__ void k_hist3(const int* __restrict__ dst, const int* __restrict__ et,
                        int* __restrict__ deg3, int E){
  int e = blockIdx.x*blockDim.x + threadIdx.x;
  if(e<E) atomicAdd(&deg3[dst[e]*3 + et[e]], 1);
}

__global__ void k_scan1(const int* __restrict__ deg, int n, int* __restrict__ part, int* __restrict__ bsum){
  __shared__ int s[256];
  int t = threadIdx.x;
  int base = blockIdx.x*1024 + t*4;
  int v[4]; int sum=0;
  #pragma unroll
  for(int k=0;k<4;k++){ int i=base+k; int d=(i<n)?deg[i]:0; sum+=d; v[k]=sum; }
  s[t]=sum; __syncthreads();
  for(int off=1;off<256;off<<=1){
    int add = (t>=off)? s[t-off] : 0;
    __syncthreads();
    s[t]+=add;
    __syncthreads();
  }
  int excl = (t>0)? s[t-1] : 0;
  #pragma unroll
  for(int k=0;k<4;k++){ int i=base+k; if(i<n) part[i]=v[k]+excl; }
  if(t==255) bsum[blockIdx.x] = s[255];
}

__global__ void k_scan2(const int* __restrict__ bsum, int nb, int* __restrict__ carry){
  if(threadIdx.x==0 && blockIdx.x==0){
    int c=0;
    for(int b=0;b<nb;b++){ carry[b]=c; c+=bsum[b]; }
  }
}

__global__ void k_finalize(const int* __restrict__ part, const int* __restrict__ deg,
                           const int* __restrict__ carry, int n,
                           int* __restrict__ rowptr, int* __restrict__ cursor){
  int i = blockIdx.x*blockDim.x + threadIdx.x;
  if(i>=n) return;
  int incl = part[i] + carry[i>>10];
  rowptr[i+1] = incl;
  cursor[i] = incl - deg[i];
  if(i==0) rowptr[0]=0;
}

__global__ void k_fill3(const int* __restrict__ src, const int* __restrict__ dst,
                        const int* __restrict__ et, int* __restrict__ cursor,
                        int* __restrict__ pay, int E){
  int e = blockIdx.x*blockDim.x + threadIdx.x;
  if(e>=E) return;
  int pos = atomicAdd(&cursor[dst[e]*3 + et[e]], 1);
  pay[pos] = src[e];
}

// gather, wave per (node,type): s[n, t*128+c] = sum typed in-edges xb[src].
__global__ void k_gather3_b(const f16* __restrict__ xb, const int* __restrict__ rp3,
                            const int* __restrict__ pay, f16* __restrict__ s, int N3){
  int wid = blockIdx.x*4 + (threadIdx.x>>6);
  if(wid >= N3) return;
  int lane = threadIdx.x & 63;
  int c = lane*2;
  int e0 = rp3[wid], e1 = rp3[wid+1];
  float a = 0.f, b = 0.f;
  int i = e0;
  for(; i+4 <= e1; i+=4){
    int p0 = pay[i], p1 = pay[i+1], p2 = pay[i+2], p3 = pay[i+3];
    v2hf v0 = *(const v2hf*)&xb[(size_t)p0*128 + c];
    v2hf v1 = *(const v2hf*)&xb[(size_t)p1*128 + c];
    v2hf v2 = *(const v2hf*)&xb[(size_t)p2*128 + c];
    v2hf v3 = *(const v2hf*)&xb[(size_t)p3*128 + c];
    a += (float)v0[0]+(float)v1[0]+(float)v2[0]+(float)v3[0];
    b += (float)v0[1]+(float)v1[1]+(float)v2[1]+(float)v3[1];
  }
  for(; i < e1; i++){
    v2hf v = *(const v2hf*)&xb[(size_t)pay[i]*128 + c];
    a += (float)v[0]; b += (float)v[1];
  }
  int n = wid/3;
  int t = wid - n*3;
  v2hf o; o[0] = (f16)a; o[1] = (f16)b;
  *(v2hf*)&s[(size_t)n*384 + t*128 + c] = o;
}

// Fused gi+gh GEMM + GRU, f16 master. 32 rows/block, 256 threads (4 waves).
// Wave w col-tiles {w,w+4,w+8} => feature slice jf in [32w,32w+32) across all
// 3 gates for gi AND gh => GRU in-register. x_old read from LDS Ax (free).
#define SSTR 392   // 384+8
#define XSTR 136   // 128+8
__global__ __launch_bounds__(256,2) void k_mega2(
    const f16* __restrict__ xb_old, f16* __restrict__ xb_new,
    const f16* __restrict__ s, const f16* __restrict__ WpF,
    const int* __restrict__ deg3, const float* __restrict__ mbp,
    const float* __restrict__ b_ih, const float* __restrict__ b_hh, int M)
{
  __shared__ f16 Ss[32*SSTR];   // 24.5 KB
  __shared__ f16 Ax[32*XSTR];   //  8.5 KB
  int tid = threadIdx.x, lane = tid & 63, w = tid >> 6;
  int lrow = lane & 31, q = lane >> 5;
  int row0 = blockIdx.x * 32;

  // stage xb rows -> Ax (direct f16 copy): 512 chunks, 2/thread
  #pragma unroll
  for(int p=0;p<2;p++){
    int ch = tid + p*256;
    int row = ch>>4, c8 = (ch&15)*8;
    int gr = row0 + row; if(gr >= M) gr = M-1;
    *(v8hf*)&Ax[row*XSTR + c8] = *(const v8hf*)(xb_old + (size_t)gr*128 + c8);
  }
  // stage s rows -> Ss: 1536 chunks, 6/thread
  #pragma unroll
  for(int p=0;p<6;p++){
    int ch = tid + p*256;
    int row = ch/48, c8 = (ch%48)*8;
    int gr = row0 + row; if(gr >= M) gr = M-1;
    *(v8hf*)&Ss[row*SSTR + c8] = *(const v8hf*)(s + (size_t)gr*384 + c8);
  }
  __syncthreads();

  v16f agi[3] = {};
  v16f agh[3] = {};

  // gh: K=128 over Ax
  #pragma unroll
  for(int ks=0; ks<8; ks++){
    int kb = ks*16 + q*8;
    v8hf a0 = *(const v8hf*)&Ax[lrow*XSTR + kb];
    #pragma unroll
    for(int ct=0; ct<3; ct++){
      int tile = ct*4 + w;
      v8hf bh = *(const v8hf*)(WpF + GI_F + (size_t)(tile*8 + ks)*512 + lane*8);
      agh[ct] = __builtin_amdgcn_mfma_f32_32x32x16_f16(a0, bh, agh[ct], 0,0,0);
    }
  }
  // gi: K=384 over Ss
  #pragma unroll
  for(int ks=0; ks<24; ks++){
    int kb = ks*16 + q*8;
    v8hf a0 = *(const v8hf*)&Ss[lrow*SSTR + kb];
    #pragma unroll
    for(int ct=0; ct<3; ct++){
      int tile = ct*4 + w;
      v8hf bh = *(const v8hf*)(WpF + (size_t)(tile*24 + ks)*512 + lane*8);
      agi[ct] = __builtin_amdgcn_mfma_f32_32x32x16_f16(a0, bh, agi[ct], 0,0,0);
    }
  }

  // GRU epilogue in-register. jf = this lane's feature; x_old from LDS.
  int jf = w*32 + lrow;
  float bi0 = b_ih[jf],     bh0 = b_hh[jf];
  float bi1 = b_ih[128+jf], bh1 = b_hh[128+jf];
  float bi2 = b_ih[256+jf], bh2 = b_hh[256+jf];
  float mb[3][3];
  #pragma unroll
  for(int t=0;t<3;t++){
    mb[t][0] = mbp[t*384 + jf];
    mb[t][1] = mbp[t*384 + 128 + jf];
    mb[t][2] = mbp[t*384 + 256 + jf];
  }
  int rq4 = 4*q;
  #pragma unroll
  for(int r=0;r<16;r++){
    int gl = (r&3) + 8*(r>>2) + rq4;          // local row 0..31
    int gr = row0 + gl;
    if(gr >= M) continue;
    const int* dq = &deg3[gr*3];
    float d0 = (float)dq[0], d1 = (float)dq[1], d2 = (float)dq[2];
    float ir  = agi[0][r] + bi0 + d0*mb[0][0] + d1*mb[1][0] + d2*mb[2][0];
    float iz  = agi[1][r] + bi1 + d0*mb[0][1] + d1*mb[1][1] + d2*mb[2][1];
    float in_ = agi[2][r] + bi2 + d0*mb[0][2] + d1*mb[1][2] + d2*mb[2][2];
    float hr  = agh[0][r] + bh0;
    float hz  = agh[1][r] + bh1;
    float hn  = agh[2][r] + bh2;
    float rg = sigf(ir + hr);
    float zg = sigf(iz + hz);
    float nn = tanhf(in_ + rg*hn);
    float xo = (float)Ax[gl*XSTR + jf];
    float xv = (1.f - zg)*nn + zg*xo;
    xb_new[(size_t)gr*128 + jf] = (f16)xv;
  }
}

__device__ __forceinline__ int lb_batch(const int* __restrict__ batch, int N, int g){
  int lo=0, hi=N;
  while(lo<hi){ int mid=(lo+hi)>>1; if(batch[mid]<g) lo=mid+1; else hi=mid; }
  return lo;
}

__global__ void k_pool2(const f16* __restrict__ xb, const int* __restrict__ batch,
                        float* __restrict__ pooled, int N){
  int g = blockIdx.x, slice = blockIdx.y;
  int j = threadIdx.x;
  int lo = lb_batch(batch,N,g), hi = lb_batch(batch,N,g+1);
  float acc = 0.f;
  for(int r=lo+slice; r<hi; r+=32) acc += (float)xb[(size_t)r*128 + j];
  atomicAdd(&pooled[g*128+j], acc);
}

__global__ void k_head(const float* __restrict__ pooled, const int* __restrict__ batch, int N,
                       const float* __restrict__ W1, const float* __restrict__ b1,
                       const float* __restrict__ W2, const float* __restrict__ b2,
                       float* __restrict__ out){
  int g = blockIdx.x; int j = threadIdx.x;
  __shared__ float p[128];
  __shared__ float red[128];
  int lo = lb_batch(batch,N,g), hi = lb_batch(batch,N,g+1);
  float c = (float)(hi-lo); if(c < 1.f) c = 1.f;
  p[j] = pooled[g*128+j] / c;
  __syncthreads();
  float acc = b1[j];
  #pragma unroll 4
  for(int i=0;i<128;i++) acc += W1[j*128+i]*p[i];
  float v = (acc>0.f?acc:0.f) * W2[j];
  red[j] = v; __syncthreads();
  for(int s=64;s>0;s>>=1){ if(j<s) red[j]+=red[j+s]; __syncthreads(); }
  if(j==0) out[g] = red[0] + b2[0];
}

extern "C" void kernel_launch(void* const* d_in, const int* in_sizes, int n_in,
                              void* d_out, int out_size, void* d_ws, size_t ws_size,
                              hipStream_t stream){
  const int*   x_type    = (const int*)d_in[0];
  const int*   x_tok     = (const int*)d_in[1];
  const float* x_small   = (const float*)d_in[2];
  const int*   edge_index= (const int*)d_in[3];
  const int*   edge_type = (const int*)d_in[4];
  const int*   batch     = (const int*)d_in[5];
  const float* type_emb  = (const float*)d_in[6];
  const float* tok_emb   = (const float*)d_in[7];
  const float* msg_W     = (const float*)d_in[8];
  const float* msg_b     = (const float*)d_in[9];
  const float* W_ih      = (const float*)d_in[10];
  const float* W_hh      = (const float*)d_in[11];
  const float* b_ih      = (const float*)d_in[12];
  const float* b_hh      = (const float*)d_in[13];
  const float* pW1       = (const float*)d_in[14];
  const float* pb1       = (const float*)d_in[15];
  const float* pW2       = (const float*)d_in[16];
  const float* pb2       = (const float*)d_in[17];
  float* out = (float*)d_out;

  int N = in_sizes[0];
  int E = in_sizes[3]/2;
  const int* src = edge_index;
  const int* dst = edge_index + E;
  int n3 = 3*N;
  int nch = (n3+1023)/1024;

  char* w = (char*)d_ws;
  size_t off = 0;
  auto alloc = [&](size_t bytes)->char*{ char* p = w + off; off += (bytes + 511) & ~511ull; return p; };
  f16*   xb0    = (f16*)alloc((size_t)N*128*2);       // ping (25.6 MB)
  f16*   xb1    = (f16*)alloc((size_t)N*128*2);       // pong (25.6 MB)
  f16*   s      = (f16*)alloc((size_t)N*384*2);       // gathered sums (76.8 MB)
  int*   deg3   = (int*)alloc((size_t)n3*4);
  int*   part   = (int*)alloc((size_t)n3*4);
  int*   rp3    = (int*)alloc((size_t)(n3+1)*4);
  int*   cursor = (int*)alloc((size_t)n3*4);
  int*   pay    = (int*)alloc((size_t)E*4);
  int*   bsum   = (int*)alloc((size_t)nch*4);
  int*   carry  = (int*)alloc((size_t)nch*4);
  float* Wc     = (float*)alloc((size_t)147456*4);
  f16*   WpF    = (f16*)alloc((size_t)(GI_F+GH_F)*2);
  float* mbp    = (float*)alloc((size_t)1152*4);
  float* pooled = (float*)alloc(64*128*4);
  if(off > ws_size){
    k_diag<<<1,64,0,stream>>>(out, out_size, 1.0e6f + (float)(ws_size>>20));
    return;
  }

  const int tb = 256;
  hipMemsetAsync(deg3, 0, (size_t)n3*4, stream);
  k_wcomb   <<<576, 256, 0, stream>>>(W_ih, msg_W, Wc);
  k_mbp     <<<5, 256, 0, stream>>>(W_ih, msg_b, mbp);
  k_wprep   <<<(GI_F+GH_F+255)/256, 256, 0, stream>>>(Wc, W_hh, WpF);
  k_hist3   <<<(E+tb-1)/tb, tb, 0, stream>>>(dst, edge_type, deg3, E);
  k_scan1   <<<nch, 256, 0, stream>>>(deg3, n3, part, bsum);
  k_scan2   <<<1, 64, 0, stream>>>(bsum, nch, carry);
  k_finalize<<<(n3+tb-1)/tb, tb, 0, stream>>>(part, deg3, carry, n3, rp3, cursor);
  k_fill3   <<<(E+tb-1)/tb, tb, 0, stream>>>(src, dst, edge_type, cursor, pay, E);
  k_embed   <<<N, 128, 0, stream>>>(x_type, x_tok, x_small, type_emb, tok_emb, xb0, N);

  int nblk = (N+31)/32;
  f16* xin = xb0;
  f16* xout = xb1;
  for(int it=0; it<8; it++){
    k_gather3_b<<<(n3+3)/4, 256, 0, stream>>>(xin, rp3, pay, s, n3);
    k_mega2    <<<nblk, 256, 0, stream>>>(xin, xout, s, WpF, deg3, mbp, b_ih, b_hh, N);
    f16* tmp = xin; xin = xout; xout = tmp;
  }
  // final state is in xin after the swap
  hipMemsetAsync(pooled, 0, 64*128*4, stream);
  k_pool2<<<dim3(64,32), 128, 0, stream>>>(xin, batch, pooled, N);
  k_head <<<64, 128, 0, stream>>>(pooled, batch, N, pW1, pb1, pW2, pb2, out);
}

// Round 11
// 1543.031 us; speedup vs baseline: 2.3657x; 1.3083x over previous
//
#include <hip/hip_runtime.h>
#include <stdint.h>

// GGNN round 11: f16 master state, split gather + f16 MFMA iteration.
//   s_t[n] = sum_{e:dst=n,type=t} xb[src[e]]        (k_gather3_b, wave/(node,type))
//   k_mega2 (32-row block): gi = s@Wc^T (K=384, f16), gh = xb@W_hh^T (K=128, f16),
//     GRU in-register -> xb_new (f16). xb ping-pong breaks gather/write race.
// R11 deltas vs R10 (all k_mega2): launch_bounds(256,3); deg3 staged in LDS;
// fast tanh/sigmoid (__expf + __fdividef); coalesced xb_new stores via Ax reuse.
// absmax has sat at exactly 1 bf16-ulp (6.1e-5) for 3 rounds => at comparison
// floor; precision headroom ~6x, f16 single weights everywhere is safe.

typedef _Float16 f16;
typedef _Float16 v8hf __attribute__((ext_vector_type(8)));
typedef _Float16 v2hf __attribute__((ext_vector_type(2)));
typedef float    v16f __attribute__((ext_vector_type(16)));

#define GI_F 147456   // 12 tiles * 24 ks * 512
#define GH_F 49152    // 12 tiles *  8 ks * 512

__device__ __forceinline__ float sigf(float a){
  return __fdividef(1.0f, 1.0f + __expf(-a));
}
__device__ __forceinline__ float tanhf_fast(float a){
  return 1.0f - __fdividef(2.0f, __expf(2.0f*a) + 1.0f);
}

__global__ void k_diag(float* out, int n, float v){
  int i = threadIdx.x; if(i<n) out[i] = v;
}

__global__ void k_embed(const int* __restrict__ xtype, const int* __restrict__ xtok,
                        const float* __restrict__ xsmall,
                        const float* __restrict__ temb, const float* __restrict__ kemb,
                        f16* __restrict__ xb, int N){
  int n = blockIdx.x; int j = threadIdx.x;
  if(n>=N) return;
  float v;
  if(j<32)       v = temb[xtype[n]*32 + j];
  else if(j<64)  v = kemb[xtok[n]*32 + (j-32)];
  else           v = xsmall[(size_t)n*64 + (j-64)];
  xb[(size_t)n*128 + j] = (f16)v;
}

// Wc[o2][K] = sum_k2 W_ih[o2,k2] * msg_W[K>>7][k2][K&127]
__global__ void k_wcomb(const float* __restrict__ W_ih, const float* __restrict__ msg_W,
                        float* __restrict__ Wc){
  int i = blockIdx.x*256 + threadIdx.x;
  if(i >= 147456) return;
  int o2 = i/384, K = i%384;
  const float* wr = W_ih + o2*128;
  const float* mc = msg_W + (K>>7)*16384 + (K&127);
  float acc = 0.f;
  #pragma unroll 4
  for(int k2=0;k2<128;k2++) acc += wr[k2]*mc[k2*128];
  Wc[i] = acc;
}

// mbp[t][o2] = sum_k2 W_ih[o2,k2]*msg_b[t,k2]
__global__ void k_mbp(const float* __restrict__ W_ih, const float* __restrict__ msg_b,
                      float* __restrict__ mbp){
  int i = blockIdx.x*256 + threadIdx.x;
  if(i >= 1152) return;
  int t = i/384, o2 = i%384;
  const float* wr = W_ih + o2*128;
  const float* mb = msg_b + t*128;
  float acc = 0.f;
  #pragma unroll 4
  for(int k2=0;k2<128;k2++) acc += wr[k2]*mb[k2];
  mbp[i] = acc;
}

// Pack weights f16, MFMA B-frag order: n = tile*32+(lane&31), k = ks*16+(lane>>5)*8+j
__global__ void k_wprep(const float* __restrict__ Wc, const float* __restrict__ W_hh,
                        f16* __restrict__ WpF){
  int i = blockIdx.x*256 + threadIdx.x;
  if(i >= GI_F + GH_F) return;
  float w; int lane, j;
  if(i < GI_F){
    int grp = i/512, rem = i%512;
    lane = rem/8; j = rem%8;
    int tile = grp/24, ks = grp%24;
    int n = tile*32 + (lane&31);
    int k = ks*16 + (lane>>5)*8 + j;
    w = Wc[n*384 + k];
  } else {
    int i2 = i - GI_F;
    int grp = i2/512, rem = i2%512;
    lane = rem/8; j = rem%8;
    int tile = grp/8, ks = grp%8;
    int n = tile*32 + (lane&31);
    int k = ks*16 + (lane>>5)*8 + j;
    w = W_hh[n*128 + k];
  }
  WpF[i] = (f16)w;
}

__global__ void k_hist3(const int* __restrict__ dst, const int* __restrict__ et,
                        int* __restrict__ deg3, int E){
  int e = blockIdx.x*blockDim.x + threadIdx.x;
  if(e<E) atomicAdd(&deg3[dst[e]*3 + et[e]], 1);
}

__global__ void k_scan1(const int* __restrict__ deg, int n, int* __restrict__ part, int* __restrict__ bsum){
  __shared__ int s[256];
  int t = threadIdx.x;
  int base = blockIdx.x*1024 + t*4;
  int v[4]; int sum=0;
  #pragma unroll
  for(int k=0;k<4;k++){ int i=base+k; int d=(i<n)?deg[i]:0; sum+=d; v[k]=sum; }
  s[t]=sum; __syncthreads();
  for(int off=1;off<256;off<<=1){
    int add = (t>=off)? s[t-off] : 0;
    __syncthreads();
    s[t]+=add;
    __syncthreads();
  }
  int excl = (t>0)? s[t-1] : 0;
  #pragma unroll
  for(int k=0;k<4;k++){ int i=base+k; if(i<n) part[i]=v[k]+excl; }
  if(t==255) bsum[blockIdx.x] = s[255];
}

__global__ void k_scan2(const int* __restrict__ bsum, int nb, int* __restrict__ carry){
  if(threadIdx.x==0 && blockIdx.x==0){
    int c=0;
    for(int b=0;b<nb;b++){ carry[b]=c; c+=bsum[b]; }
  }
}

__global__ void k_finalize(const int* __restrict__ part, const int* __restrict__ deg,
                           const int* __restrict__ carry, int n,
                           int* __restrict__ rowptr, int* __restrict__ cursor){
  int i = blockIdx.x*blockDim.x + threadIdx.x;
  if(i>=n) return;
  int incl = part[i] + carry[i>>10];
  rowptr[i+1] = incl;
  cursor[i] = incl - deg[i];
  if(i==0) rowptr[0]=0;
}

__global__ void k_fill3(const int* __restrict__ src, const int* __restrict__ dst,
                        const int* __restrict__ et, int* __restrict__ cursor,
                        int* __restrict__ pay, int E){
  int e = blockIdx.x*blockDim.x + threadIdx.x;
  if(e>=E) return;
  int pos = atomicAdd(&cursor[dst[e]*3 + et[e]], 1);
  pay[pos] = src[e];
}

// gather, wave per (node,type): s[n, t*128+c] = sum typed in-edges xb[src].
__global__ void k_gather3_b(const f16* __restrict__ xb, const int* __restrict__ rp3,
                            const int* __restrict__ pay, f16* __restrict__ s, int N3){
  int wid = blockIdx.x*4 + (threadIdx.x>>6);
  if(wid >= N3) return;
  int lane = threadIdx.x & 63;
  int c = lane*2;
  int e0 = rp3[wid], e1 = rp3[wid+1];
  float a = 0.f, b = 0.f;
  int i = e0;
  for(; i+4 <= e1; i+=4){
    int p0 = pay[i], p1 = pay[i+1], p2 = pay[i+2], p3 = pay[i+3];
    v2hf v0 = *(const v2hf*)&xb[(size_t)p0*128 + c];
    v2hf v1 = *(const v2hf*)&xb[(size_t)p1*128 + c];
    v2hf v2 = *(const v2hf*)&xb[(size_t)p2*128 + c];
    v2hf v3 = *(const v2hf*)&xb[(size_t)p3*128 + c];
    a += (float)v0[0]+(float)v1[0]+(float)v2[0]+(float)v3[0];
    b += (float)v0[1]+(float)v1[1]+(float)v2[1]+(float)v3[1];
  }
  for(; i < e1; i++){
    v2hf v = *(const v2hf*)&xb[(size_t)pay[i]*128 + c];
    a += (float)v[0]; b += (float)v[1];
  }
  int n = wid/3;
  int t = wid - n*3;
  v2hf o; o[0] = (f16)a; o[1] = (f16)b;
  *(v2hf*)&s[(size_t)n*384 + t*128 + c] = o;
}

// Fused gi+gh GEMM + GRU, f16 master. 32 rows/block, 256 threads (4 waves).
// Wave w col-tiles {w,w+4,w+8} => feature slice jf in [32w,32w+32) across all
// 3 gates for gi AND gh => GRU in-register. x_old from LDS Ax; result written
// back into Ax then stored coalesced.
#define SSTR 392   // 384+8
#define XSTR 136   // 128+8
__global__ __launch_bounds__(256,3) void k_mega2(
    const f16* __restrict__ xb_old, f16* __restrict__ xb_new,
    const f16* __restrict__ s, const f16* __restrict__ WpF,
    const int* __restrict__ deg3, const float* __restrict__ mbp,
    const float* __restrict__ b_ih, const float* __restrict__ b_hh, int M)
{
  __shared__ f16 Ss[32*SSTR];   // 24.5 KB
  __shared__ f16 Ax[32*XSTR];   //  8.5 KB
  __shared__ float Dg[96];      // deg3 for this block's 32 rows
  int tid = threadIdx.x, lane = tid & 63, w = tid >> 6;
  int lrow = lane & 31, q = lane >> 5;
  int row0 = blockIdx.x * 32;

  // stage xb rows -> Ax: 512 chunks, 2/thread
  #pragma unroll
  for(int p=0;p<2;p++){
    int ch = tid + p*256;
    int row = ch>>4, c8 = (ch&15)*8;
    int gr = row0 + row; if(gr >= M) gr = M-1;
    *(v8hf*)&Ax[row*XSTR + c8] = *(const v8hf*)(xb_old + (size_t)gr*128 + c8);
  }
  // stage s rows -> Ss: 1536 chunks, 6/thread
  #pragma unroll
  for(int p=0;p<6;p++){
    int ch = tid + p*256;
    int row = ch/48, c8 = (ch%48)*8;
    int gr = row0 + row; if(gr >= M) gr = M-1;
    *(v8hf*)&Ss[row*SSTR + c8] = *(const v8hf*)(s + (size_t)gr*384 + c8);
  }
  // stage deg3 -> Dg
  if(tid < 96){
    int node = row0 + tid/3;
    Dg[tid] = (node < M) ? (float)deg3[node*3 + (tid - (tid/3)*3)] : 0.f;
  }
  __syncthreads();

  v16f agi[3] = {};
  v16f agh[3] = {};

  // gh: K=128 over Ax
  #pragma unroll
  for(int ks=0; ks<8; ks++){
    int kb = ks*16 + q*8;
    v8hf a0 = *(const v8hf*)&Ax[lrow*XSTR + kb];
    #pragma unroll
    for(int ct=0; ct<3; ct++){
      int tile = ct*4 + w;
      v8hf bh = *(const v8hf*)(WpF + GI_F + (size_t)(tile*8 + ks)*512 + lane*8);
      agh[ct] = __builtin_amdgcn_mfma_f32_32x32x16_f16(a0, bh, agh[ct], 0,0,0);
    }
  }
  // gi: K=384 over Ss
  #pragma unroll
  for(int ks=0; ks<24; ks++){
    int kb = ks*16 + q*8;
    v8hf a0 = *(const v8hf*)&Ss[lrow*SSTR + kb];
    #pragma unroll
    for(int ct=0; ct<3; ct++){
      int tile = ct*4 + w;
      v8hf bh = *(const v8hf*)(WpF + (size_t)(tile*24 + ks)*512 + lane*8);
      agi[ct] = __builtin_amdgcn_mfma_f32_32x32x16_f16(a0, bh, agi[ct], 0,0,0);
    }
  }

  // GRU epilogue in-register. jf = this lane's feature; x_old from LDS.
  int jf = w*32 + lrow;
  float bi0 = b_ih[jf],     bh0 = b_hh[jf];
  float bi1 = b_ih[128+jf], bh1 = b_hh[128+jf];
  float bi2 = b_ih[256+jf], bh2 = b_hh[256+jf];
  float mb[3][3];
  #pragma unroll
  for(int t=0;t<3;t++){
    mb[t][0] = mbp[t*384 + jf];
    mb[t][1] = mbp[t*384 + 128 + jf];
    mb[t][2] = mbp[t*384 + 256 + jf];
  }
  int rq4 = 4*q;
  #pragma unroll
  for(int r=0;r<16;r++){
    int gl = (r&3) + 8*(r>>2) + rq4;          // local row 0..31
    float d0 = Dg[gl*3], d1 = Dg[gl*3+1], d2 = Dg[gl*3+2];
    float ir  = agi[0][r] + bi0 + d0*mb[0][0] + d1*mb[1][0] + d2*mb[2][0];
    float iz  = agi[1][r] + bi1 + d0*mb[0][1] + d1*mb[1][1] + d2*mb[2][1];
    float in_ = agi[2][r] + bi2 + d0*mb[0][2] + d1*mb[1][2] + d2*mb[2][2];
    float hr  = agh[0][r] + bh0;
    float hz  = agh[1][r] + bh1;
    float hn  = agh[2][r] + bh2;
    float rg = sigf(ir + hr);
    float zg = sigf(iz + hz);
    float nn = tanhf_fast(in_ + rg*hn);
    float xo = (float)Ax[gl*XSTR + jf];
    Ax[gl*XSTR + jf] = (f16)((1.f - zg)*nn + zg*xo);   // in-place, own slot
  }
  __syncthreads();
  // coalesced writeback from Ax
  #pragma unroll
  for(int p=0;p<2;p++){
    int ch = tid + p*256;
    int row = ch>>4, c8 = (ch&15)*8;
    int gr = row0 + row;
    if(gr < M)
      *(v8hf*)(xb_new + (size_t)gr*128 + c8) = *(const v8hf*)&Ax[row*XSTR + c8];
  }
}

__device__ __forceinline__ int lb_batch(const int* __restrict__ batch, int N, int g){
  int lo=0, hi=N;
  while(lo<hi){ int mid=(lo+hi)>>1; if(batch[mid]<g) lo=mid+1; else hi=mid; }
  return lo;
}

__global__ void k_pool2(const f16* __restrict__ xb, const int* __restrict__ batch,
                        float* __restrict__ pooled, int N){
  int g = blockIdx.x, slice = blockIdx.y;
  int j = threadIdx.x;
  int lo = lb_batch(batch,N,g), hi = lb_batch(batch,N,g+1);
  float acc = 0.f;
  for(int r=lo+slice; r<hi; r+=32) acc += (float)xb[(size_t)r*128 + j];
  atomicAdd(&pooled[g*128+j], acc);
}

__global__ void k_head(const float* __restrict__ pooled, const int* __restrict__ batch, int N,
                       const float* __restrict__ W1, const float* __restrict__ b1,
                       const float* __restrict__ W2, const float* __restrict__ b2,
                       float* __restrict__ out){
  int g = blockIdx.x; int j = threadIdx.x;
  __shared__ float p[128];
  __shared__ float red[128];
  int lo = lb_batch(batch,N,g), hi = lb_batch(batch,N,g+1);
  float c = (float)(hi-lo); if(c < 1.f) c = 1.f;
  p[j] = pooled[g*128+j] / c;
  __syncthreads();
  float acc = b1[j];
  #pragma unroll 4
  for(int i=0;i<128;i++) acc += W1[j*128+i]*p[i];
  float v = (acc>0.f?acc:0.f) * W2[j];
  red[j] = v; __syncthreads();
  for(int s=64;s>0;s>>=1){ if(j<s) red[j]+=red[j+s]; __syncthreads(); }
  if(j==0) out[g] = red[0] + b2[0];
}

extern "C" void kernel_launch(void* const* d_in, const int* in_sizes, int n_in,
                              void* d_out, int out_size, void* d_ws, size_t ws_size,
                              hipStream_t stream){
  const int*   x_type    = (const int*)d_in[0];
  const int*   x_tok     = (const int*)d_in[1];
  const float* x_small   = (const float*)d_in[2];
  const int*   edge_index= (const int*)d_in[3];
  const int*   edge_type = (const int*)d_in[4];
  const int*   batch     = (const int*)d_in[5];
  const float* type_emb  = (const float*)d_in[6];
  const float* tok_emb   = (const float*)d_in[7];
  const float* msg_W     = (const float*)d_in[8];
  const float* msg_b     = (const float*)d_in[9];
  const float* W_ih      = (const float*)d_in[10];
  const float* W_hh      = (const float*)d_in[11];
  const float* b_ih      = (const float*)d_in[12];
  const float* b_hh      = (const float*)d_in[13];
  const float* pW1       = (const float*)d_in[14];
  const float* pb1       = (const float*)d_in[15];
  const float* pW2       = (const float*)d_in[16];
  const float* pb2       = (const float*)d_in[17];
  float* out = (float*)d_out;

  int N = in_sizes[0];
  int E = in_sizes[3]/2;
  const int* src = edge_index;
  const int* dst = edge_index + E;
  int n3 = 3*N;
  int nch = (n3+1023)/1024;

  char* w = (char*)d_ws;
  size_t off = 0;
  auto alloc = [&](size_t bytes)->char*{ char* p = w + off; off += (bytes + 511) & ~511ull; return p; };
  f16*   xb0    = (f16*)alloc((size_t)N*128*2);       // ping (25.6 MB)
  f16*   xb1    = (f16*)alloc((size_t)N*128*2);       // pong (25.6 MB)
  f16*   s      = (f16*)alloc((size_t)N*384*2);       // gathered sums (76.8 MB)
  int*   deg3   = (int*)alloc((size_t)n3*4);
  int*   part   = (int*)alloc((size_t)n3*4);
  int*   rp3    = (int*)alloc((size_t)(n3+1)*4);
  int*   cursor = (int*)alloc((size_t)n3*4);
  int*   pay    = (int*)alloc((size_t)E*4);
  int*   bsum   = (int*)alloc((size_t)nch*4);
  int*   carry  = (int*)alloc((size_t)nch*4);
  float* Wc     = (float*)alloc((size_t)147456*4);
  f16*   WpF    = (f16*)alloc((size_t)(GI_F+GH_F)*2);
  float* mbp    = (float*)alloc((size_t)1152*4);
  float* pooled = (float*)alloc(64*128*4);
  if(off > ws_size){
    k_diag<<<1,64,0,stream>>>(out, out_size, 1.0e6f + (float)(ws_size>>20));
    return;
  }

  const int tb = 256;
  hipMemsetAsync(deg3, 0, (size_t)n3*4, stream);
  k_wcomb   <<<576, 256, 0, stream>>>(W_ih, msg_W, Wc);
  k_mbp     <<<5, 256, 0, stream>>>(W_ih, msg_b, mbp);
  k_wprep   <<<(GI_F+GH_F+255)/256, 256, 0, stream>>>(Wc, W_hh, WpF);
  k_hist3   <<<(E+tb-1)/tb, tb, 0, stream>>>(dst, edge_type, deg3, E);
  k_scan1   <<<nch, 256, 0, stream>>>(deg3, n3, part, bsum);
  k_scan2   <<<1, 64, 0, stream>>>(bsum, nch, carry);
  k_finalize<<<(n3+tb-1)/tb, tb, 0, stream>>>(part, deg3, carry, n3, rp3, cursor);
  k_fill3   <<<(E+tb-1)/tb, tb, 0, stream>>>(src, dst, edge_type, cursor, pay, E);
  k_embed   <<<N, 128, 0, stream>>>(x_type, x_tok, x_small, type_emb, tok_emb, xb0, N);

  int nblk = (N+31)/32;
  f16* xin = xb0;
  f16* xout = xb1;
  for(int it=0; it<8; it++){
    k_gather3_b<<<(n3+3)/4, 256, 0, stream>>>(xin, rp3, pay, s, n3);
    k_mega2    <<<nblk, 256, 0, stream>>>(xin, xout, s, WpF, deg3, mbp, b_ih, b_hh, N);
    f16* tmp = xin; xin = xout; xout = tmp;
  }
  // final state is in xin after the swap
  hipMemsetAsync(pooled, 0, 64*128*4, stream);
  k_pool2<<<dim3(64,32), 128, 0, stream>>>(xin, batch, pooled, N);
  k_head <<<64, 128, 0, stream>>>(pooled, batch, N, pW1, pb1, pW2, pb2, out);
}

// Round 12
// 1327.276 us; speedup vs baseline: 2.7503x; 1.1626x over previous
//
#include <hip/hip_runtime.h>
#include <stdint.h>

// GGNN round 12: f16 master state, split gather + f16 MFMA iteration.
//   s_t[n] = sum_{e:dst=n,type=t} xb[src[e]]   (k_gather3_b: wave/node, 3 interleaved chains)
//   k_mega2 (32-row block): gi = s@Wc^T (K=384) -> pack f16, gh = xb@W_hh^T (K=128),
//     GRU in-register -> xb_new. Ping-pong xb breaks gather/write race.
// R12 deltas: gi-first + f16 acc pack (96->72 live acc regs => (256,3) achievable,
// 3 blocks/CU); gather interleaves the 3 type-bins per node for 3x load ILP.

typedef _Float16 f16;
typedef _Float16 v8hf __attribute__((ext_vector_type(8)));
typedef _Float16 v2hf __attribute__((ext_vector_type(2)));
typedef float    v16f __attribute__((ext_vector_type(16)));

#define GI_F 147456   // 12 tiles * 24 ks * 512
#define GH_F 49152    // 12 tiles *  8 ks * 512

__device__ __forceinline__ float sigf(float a){
  return __fdividef(1.0f, 1.0f + __expf(-a));
}
__device__ __forceinline__ float tanhf_fast(float a){
  return 1.0f - __fdividef(2.0f, __expf(2.0f*a) + 1.0f);
}

__global__ void k_diag(float* out, int n, float v){
  int i = threadIdx.x; if(i<n) out[i] = v;
}

__global__ void k_embed(const int* __restrict__ xtype, const int* __restrict__ xtok,
                        const float* __restrict__ xsmall,
                        const float* __restrict__ temb, const float* __restrict__ kemb,
                        f16* __restrict__ xb, int N){
  int n = blockIdx.x; int j = threadIdx.x;
  if(n>=N) return;
  float v;
  if(j<32)       v = temb[xtype[n]*32 + j];
  else if(j<64)  v = kemb[xtok[n]*32 + (j-32)];
  else           v = xsmall[(size_t)n*64 + (j-64)];
  xb[(size_t)n*128 + j] = (f16)v;
}

// Wc[o2][K] = sum_k2 W_ih[o2,k2] * msg_W[K>>7][k2][K&127]
__global__ void k_wcomb(const float* __restrict__ W_ih, const float* __restrict__ msg_W,
                        float* __restrict__ Wc){
  int i = blockIdx.x*256 + threadIdx.x;
  if(i >= 147456) return;
  int o2 = i/384, K = i%384;
  const float* wr = W_ih + o2*128;
  const float* mc = msg_W + (K>>7)*16384 + (K&127);
  float acc = 0.f;
  #pragma unroll 4
  for(int k2=0;k2<128;k2++) acc += wr[k2]*mc[k2*128];
  Wc[i] = acc;
}

// mbp[t][o2] = sum_k2 W_ih[o2,k2]*msg_b[t,k2]
__global__ void k_mbp(const float* __restrict__ W_ih, const float* __restrict__ msg_b,
                      float* __restrict__ mbp){
  int i = blockIdx.x*256 + threadIdx.x;
  if(i >= 1152) return;
  int t = i/384, o2 = i%384;
  const float* wr = W_ih + o2*128;
  const float* mb = msg_b + t*128;
  float acc = 0.f;
  #pragma unroll 4
  for(int k2=0;k2<128;k2++) acc += wr[k2]*mb[k2];
  mbp[i] = acc;
}

// Pack weights f16, MFMA B-frag order: n = tile*32+(lane&31), k = ks*16+(lane>>5)*8+j
__global__ void k_wprep(const float* __restrict__ Wc, const float* __restrict__ W_hh,
                        f16* __restrict__ WpF){
  int i = blockIdx.x*256 + threadIdx.x;
  if(i >= GI_F + GH_F) return;
  float w; int lane, j;
  if(i < GI_F){
    int grp = i/512, rem = i%512;
    lane = rem/8; j = rem%8;
    int tile = grp/24, ks = grp%24;
    int n = tile*32 + (lane&31);
    int k = ks*16 + (lane>>5)*8 + j;
    w = Wc[n*384 + k];
  } else {
    int i2 = i - GI_F;
    int grp = i2/512, rem = i2%512;
    lane = rem/8; j = rem%8;
    int tile = grp/8, ks = grp%8;
    int n = tile*32 + (lane&31);
    int k = ks*16 + (lane>>5)*8 + j;
    w = W_hh[n*128 + k];
  }
  WpF[i] = (f16)w;
}

__global__ void k_hist3(const int* __restrict__ dst, const int* __restrict__ et,
                        int* __restrict__ deg3, int E){
  int e = blockIdx.x*blockDim.x + threadIdx.x;
  if(e<E) atomicAdd(&deg3[dst[e]*3 + et[e]], 1);
}

__global__ void k_scan1(const int* __restrict__ deg, int n, int* __restrict__ part, int* __restrict__ bsum){
  __shared__ int s[256];
  int t = threadIdx.x;
  int base = blockIdx.x*1024 + t*4;
  int v[4]; int sum=0;
  #pragma unroll
  for(int k=0;k<4;k++){ int i=base+k; int d=(i<n)?deg[i]:0; sum+=d; v[k]=sum; }
  s[t]=sum; __syncthreads();
  for(int off=1;off<256;off<<=1){
    int add = (t>=off)? s[t-off] : 0;
    __syncthreads();
    s[t]+=add;
    __syncthreads();
  }
  int excl = (t>0)? s[t-1] : 0;
  #pragma unroll
  for(int k=0;k<4;k++){ int i=base+k; if(i<n) part[i]=v[k]+excl; }
  if(t==255) bsum[blockIdx.x] = s[255];
}

__global__ void k_scan2(const int* __restrict__ bsum, int nb, int* __restrict__ carry){
  if(threadIdx.x==0 && blockIdx.x==0){
    int c=0;
    for(int b=0;b<nb;b++){ carry[b]=c; c+=bsum[b]; }
  }
}

__global__ void k_finalize(const int* __restrict__ part, const int* __restrict__ deg,
                           const int* __restrict__ carry, int n,
                           int* __restrict__ rowptr, int* __restrict__ cursor){
  int i = blockIdx.x*blockDim.x + threadIdx.x;
  if(i>=n) return;
  int incl = part[i] + carry[i>>10];
  rowptr[i+1] = incl;
  cursor[i] = incl - deg[i];
  if(i==0) rowptr[0]=0;
}

__global__ void k_fill3(const int* __restrict__ src, const int* __restrict__ dst,
                        const int* __restrict__ et, int* __restrict__ cursor,
                        int* __restrict__ pay, int E){
  int e = blockIdx.x*blockDim.x + threadIdx.x;
  if(e>=E) return;
  int pos = atomicAdd(&cursor[dst[e]*3 + et[e]], 1);
  pay[pos] = src[e];
}

// gather: one wave per node, the node's 3 type-bin chains interleaved (3x load ILP).
// Lane covers 2 cols. Loop bounds wave-uniform -> scalar branches.
__global__ void k_gather3_b(const f16* __restrict__ xb, const int* __restrict__ rp3,
                            const int* __restrict__ pay, f16* __restrict__ s, int N){
  int n = blockIdx.x*4 + (threadIdx.x>>6);
  if(n >= N) return;
  int lane = threadIdx.x & 63;
  int c = lane*2;
  int b = n*3;
  int i0 = rp3[b],   e0 = rp3[b+1];
  int i1 = e0,       e1 = rp3[b+2];
  int i2 = e1,       e2 = rp3[b+3];
  float a0=0.f,b0=0.f,a1=0.f,b1=0.f,a2=0.f,b2=0.f;
  while(i0<e0 && i1<e1 && i2<e2){
    int p0 = pay[i0], p1 = pay[i1], p2 = pay[i2];
    v2hf u0 = *(const v2hf*)&xb[(size_t)p0*128 + c];
    v2hf u1 = *(const v2hf*)&xb[(size_t)p1*128 + c];
    v2hf u2 = *(const v2hf*)&xb[(size_t)p2*128 + c];
    a0 += (float)u0[0]; b0 += (float)u0[1];
    a1 += (float)u1[0]; b1 += (float)u1[1];
    a2 += (float)u2[0]; b2 += (float)u2[1];
    i0++; i1++; i2++;
  }
  for(; i0<e0; i0++){ v2hf u = *(const v2hf*)&xb[(size_t)pay[i0]*128 + c]; a0+=(float)u[0]; b0+=(float)u[1]; }
  for(; i1<e1; i1++){ v2hf u = *(const v2hf*)&xb[(size_t)pay[i1]*128 + c]; a1+=(float)u[0]; b1+=(float)u[1]; }
  for(; i2<e2; i2++){ v2hf u = *(const v2hf*)&xb[(size_t)pay[i2]*128 + c]; a2+=(float)u[0]; b2+=(float)u[1]; }
  size_t o = (size_t)n*384 + c;
  v2hf t;
  t[0]=(f16)a0; t[1]=(f16)b0; *(v2hf*)&s[o]     = t;
  t[0]=(f16)a1; t[1]=(f16)b1; *(v2hf*)&s[o+128] = t;
  t[0]=(f16)a2; t[1]=(f16)b2; *(v2hf*)&s[o+256] = t;
}

// Fused gi+gh GEMM + GRU, f16 master. 32 rows/block, 256 threads (4 waves).
// Wave w col-tiles {w,w+4,w+8} => feature slice jf in [32w,32w+32) across all
// 3 gates for gi AND gh => GRU in-register. Order: gi MFMAs -> pack agi to f16
// pairs (48->24 VGPRs) -> gh MFMAs -> epilogue. Peak live acc 72 regs => (256,3).
#define SSTR 392   // 384+8
#define XSTR 136   // 128+8
__global__ __launch_bounds__(256,3) void k_mega2(
    const f16* __restrict__ xb_old, f16* __restrict__ xb_new,
    const f16* __restrict__ s, const f16* __restrict__ WpF,
    const int* __restrict__ deg3, const float* __restrict__ mbp,
    const float* __restrict__ b_ih, const float* __restrict__ b_hh, int M)
{
  __shared__ f16 Ss[32*SSTR];   // 24.5 KB
  __shared__ f16 Ax[32*XSTR];   //  8.5 KB
  __shared__ float Dg[96];      // deg3 for this block's 32 rows
  int tid = threadIdx.x, lane = tid & 63, w = tid >> 6;
  int lrow = lane & 31, q = lane >> 5;
  int row0 = blockIdx.x * 32;

  // stage xb rows -> Ax: 512 chunks, 2/thread
  #pragma unroll
  for(int p=0;p<2;p++){
    int ch = tid + p*256;
    int row = ch>>4, c8 = (ch&15)*8;
    int gr = row0 + row; if(gr >= M) gr = M-1;
    *(v8hf*)&Ax[row*XSTR + c8] = *(const v8hf*)(xb_old + (size_t)gr*128 + c8);
  }
  // stage s rows -> Ss: 1536 chunks, 6/thread
  #pragma unroll
  for(int p=0;p<6;p++){
    int ch = tid + p*256;
    int row = ch/48, c8 = (ch%48)*8;
    int gr = row0 + row; if(gr >= M) gr = M-1;
    *(v8hf*)&Ss[row*SSTR + c8] = *(const v8hf*)(s + (size_t)gr*384 + c8);
  }
  // stage deg3 -> Dg
  if(tid < 96){
    int node = row0 + tid/3;
    Dg[tid] = (node < M) ? (float)deg3[node*3 + (tid - (tid/3)*3)] : 0.f;
  }
  __syncthreads();

  // ---- gi phase: K=384 over Ss ----
  v16f agi[3] = {};
  #pragma unroll
  for(int ks=0; ks<24; ks++){
    int kb = ks*16 + q*8;
    v8hf a0 = *(const v8hf*)&Ss[lrow*SSTR + kb];
    #pragma unroll
    for(int ct=0; ct<3; ct++){
      int tile = ct*4 + w;
      v8hf bh = *(const v8hf*)(WpF + (size_t)(tile*24 + ks)*512 + lane*8);
      agi[ct] = __builtin_amdgcn_mfma_f32_32x32x16_f16(a0, bh, agi[ct], 0,0,0);
    }
  }
  // pack agi -> f16 pairs (frees 48 -> 24 regs)
  v2hf gip[3][8];
  #pragma unroll
  for(int ct=0; ct<3; ct++)
    #pragma unroll
    for(int rp=0; rp<8; rp++){
      v2hf t; t[0] = (f16)agi[ct][2*rp]; t[1] = (f16)agi[ct][2*rp+1];
      gip[ct][rp] = t;
    }

  // ---- gh phase: K=128 over Ax ----
  v16f agh[3] = {};
  #pragma unroll
  for(int ks=0; ks<8; ks++){
    int kb = ks*16 + q*8;
    v8hf a0 = *(const v8hf*)&Ax[lrow*XSTR + kb];
    #pragma unroll
    for(int ct=0; ct<3; ct++){
      int tile = ct*4 + w;
      v8hf bh = *(const v8hf*)(WpF + GI_F + (size_t)(tile*8 + ks)*512 + lane*8);
      agh[ct] = __builtin_amdgcn_mfma_f32_32x32x16_f16(a0, bh, agh[ct], 0,0,0);
    }
  }

  // GRU epilogue in-register. jf = this lane's feature; x_old from LDS.
  int jf = w*32 + lrow;
  float bi0 = b_ih[jf],     bh0 = b_hh[jf];
  float bi1 = b_ih[128+jf], bh1 = b_hh[128+jf];
  float bi2 = b_ih[256+jf], bh2 = b_hh[256+jf];
  float mb[3][3];
  #pragma unroll
  for(int t=0;t<3;t++){
    mb[t][0] = mbp[t*384 + jf];
    mb[t][1] = mbp[t*384 + 128 + jf];
    mb[t][2] = mbp[t*384 + 256 + jf];
  }
  int rq4 = 4*q;
  #pragma unroll
  for(int r=0;r<16;r++){
    int gl = (r&3) + 8*(r>>2) + rq4;          // local row 0..31
    float d0 = Dg[gl*3], d1 = Dg[gl*3+1], d2 = Dg[gl*3+2];
    float g0 = (float)gip[0][r>>1][r&1];
    float g1 = (float)gip[1][r>>1][r&1];
    float g2 = (float)gip[2][r>>1][r&1];
    float ir  = g0 + bi0 + d0*mb[0][0] + d1*mb[1][0] + d2*mb[2][0];
    float iz  = g1 + bi1 + d0*mb[0][1] + d1*mb[1][1] + d2*mb[2][1];
    float in_ = g2 + bi2 + d0*mb[0][2] + d1*mb[1][2] + d2*mb[2][2];
    float hr  = agh[0][r] + bh0;
    float hz  = agh[1][r] + bh1;
    float hn  = agh[2][r] + bh2;
    float rg = sigf(ir + hr);
    float zg = sigf(iz + hz);
    float nn = tanhf_fast(in_ + rg*hn);
    float xo = (float)Ax[gl*XSTR + jf];
    Ax[gl*XSTR + jf] = (f16)((1.f - zg)*nn + zg*xo);   // in-place, own slot
  }
  __syncthreads();
  // coalesced writeback from Ax
  #pragma unroll
  for(int p=0;p<2;p++){
    int ch = tid + p*256;
    int row = ch>>4, c8 = (ch&15)*8;
    int gr = row0 + row;
    if(gr < M)
      *(v8hf*)(xb_new + (size_t)gr*128 + c8) = *(const v8hf*)&Ax[row*XSTR + c8];
  }
}

__device__ __forceinline__ int lb_batch(const int* __restrict__ batch, int N, int g){
  int lo=0, hi=N;
  while(lo<hi){ int mid=(lo+hi)>>1; if(batch[mid]<g) lo=mid+1; else hi=mid; }
  return lo;
}

__global__ void k_pool2(const f16* __restrict__ xb, const int* __restrict__ batch,
                        float* __restrict__ pooled, int N){
  int g = blockIdx.x, slice = blockIdx.y;
  int j = threadIdx.x;
  int lo = lb_batch(batch,N,g), hi = lb_batch(batch,N,g+1);
  float acc = 0.f;
  for(int r=lo+slice; r<hi; r+=32) acc += (float)xb[(size_t)r*128 + j];
  atomicAdd(&pooled[g*128+j], acc);
}

__global__ void k_head(const float* __restrict__ pooled, const int* __restrict__ batch, int N,
                       const float* __restrict__ W1, const float* __restrict__ b1,
                       const float* __restrict__ W2, const float* __restrict__ b2,
                       float* __restrict__ out){
  int g = blockIdx.x; int j = threadIdx.x;
  __shared__ float p[128];
  __shared__ float red[128];
  int lo = lb_batch(batch,N,g), hi = lb_batch(batch,N,g+1);
  float c = (float)(hi-lo); if(c < 1.f) c = 1.f;
  p[j] = pooled[g*128+j] / c;
  __syncthreads();
  float acc = b1[j];
  #pragma unroll 4
  for(int i=0;i<128;i++) acc += W1[j*128+i]*p[i];
  float v = (acc>0.f?acc:0.f) * W2[j];
  red[j] = v; __syncthreads();
  for(int s=64;s>0;s>>=1){ if(j<s) red[j]+=red[j+s]; __syncthreads(); }
  if(j==0) out[g] = red[0] + b2[0];
}

extern "C" void kernel_launch(void* const* d_in, const int* in_sizes, int n_in,
                              void* d_out, int out_size, void* d_ws, size_t ws_size,
                              hipStream_t stream){
  const int*   x_type    = (const int*)d_in[0];
  const int*   x_tok     = (const int*)d_in[1];
  const float* x_small   = (const float*)d_in[2];
  const int*   edge_index= (const int*)d_in[3];
  const int*   edge_type = (const int*)d_in[4];
  const int*   batch     = (const int*)d_in[5];
  const float* type_emb  = (const float*)d_in[6];
  const float* tok_emb   = (const float*)d_in[7];
  const float* msg_W     = (const float*)d_in[8];
  const float* msg_b     = (const float*)d_in[9];
  const float* W_ih      = (const float*)d_in[10];
  const float* W_hh      = (const float*)d_in[11];
  const float* b_ih      = (const float*)d_in[12];
  const float* b_hh      = (const float*)d_in[13];
  const float* pW1       = (const float*)d_in[14];
  const float* pb1       = (const float*)d_in[15];
  const float* pW2       = (const float*)d_in[16];
  const float* pb2       = (const float*)d_in[17];
  float* out = (float*)d_out;

  int N = in_sizes[0];
  int E = in_sizes[3]/2;
  const int* src = edge_index;
  const int* dst = edge_index + E;
  int n3 = 3*N;
  int nch = (n3+1023)/1024;

  char* w = (char*)d_ws;
  size_t off = 0;
  auto alloc = [&](size_t bytes)->char*{ char* p = w + off; off += (bytes + 511) & ~511ull; return p; };
  f16*   xb0    = (f16*)alloc((size_t)N*128*2);       // ping (25.6 MB)
  f16*   xb1    = (f16*)alloc((size_t)N*128*2);       // pong (25.6 MB)
  f16*   s      = (f16*)alloc((size_t)N*384*2);       // gathered sums (76.8 MB)
  int*   deg3   = (int*)alloc((size_t)n3*4);
  int*   part   = (int*)alloc((size_t)n3*4);
  int*   rp3    = (int*)alloc((size_t)(n3+1)*4);
  int*   cursor = (int*)alloc((size_t)n3*4);
  int*   pay    = (int*)alloc((size_t)E*4);
  int*   bsum   = (int*)alloc((size_t)nch*4);
  int*   carry  = (int*)alloc((size_t)nch*4);
  float* Wc     = (float*)alloc((size_t)147456*4);
  f16*   WpF    = (f16*)alloc((size_t)(GI_F+GH_F)*2);
  float* mbp    = (float*)alloc((size_t)1152*4);
  float* pooled = (float*)alloc(64*128*4);
  if(off > ws_size){
    k_diag<<<1,64,0,stream>>>(out, out_size, 1.0e6f + (float)(ws_size>>20));
    return;
  }

  const int tb = 256;
  hipMemsetAsync(deg3, 0, (size_t)n3*4, stream);
  k_wcomb   <<<576, 256, 0, stream>>>(W_ih, msg_W, Wc);
  k_mbp     <<<5, 256, 0, stream>>>(W_ih, msg_b, mbp);
  k_wprep   <<<(GI_F+GH_F+255)/256, 256, 0, stream>>>(Wc, W_hh, WpF);
  k_hist3   <<<(E+tb-1)/tb, tb, 0, stream>>>(dst, edge_type, deg3, E);
  k_scan1   <<<nch, 256, 0, stream>>>(deg3, n3, part, bsum);
  k_scan2   <<<1, 64, 0, stream>>>(bsum, nch, carry);
  k_finalize<<<(n3+tb-1)/tb, tb, 0, stream>>>(part, deg3, carry, n3, rp3, cursor);
  k_fill3   <<<(E+tb-1)/tb, tb, 0, stream>>>(src, dst, edge_type, cursor, pay, E);
  k_embed   <<<N, 128, 0, stream>>>(x_type, x_tok, x_small, type_emb, tok_emb, xb0, N);

  int nblk = (N+31)/32;
  f16* xin = xb0;
  f16* xout = xb1;
  for(int it=0; it<8; it++){
    k_gather3_b<<<(N+3)/4, 256, 0, stream>>>(xin, rp3, pay, s, N);
    k_mega2    <<<nblk, 256, 0, stream>>>(xin, xout, s, WpF, deg3, mbp, b_ih, b_hh, N);
    f16* tmp = xin; xin = xout; xout = tmp;
  }
  // final state is in xin after the swap
  hipMemsetAsync(pooled, 0, 64*128*4, stream);
  k_pool2<<<dim3(64,32), 128, 0, stream>>>(xin, batch, pooled, N);
  k_head <<<64, 128, 0, stream>>>(pooled, batch, N, pW1, pb1, pW2, pb2, out);
}